// Round 11
// baseline (313.064 us; speedup 1.0000x reference)
//
#include <hip/hip_runtime.h>
#include <math.h>

// ---------------------------------------------------------------------------
// GCN via two-pass bucket radix (dst-grouped edges, zero global atomics).
// h1 = relu(dstn * S(ew * srcn*(X@W1)) + b1)
// h2 = relu(dstn * S(ew * srcn*([h1,X]@W2)) + b2) ; out = l2norm(h2)
// Gathers: cooperative edata load + v_readlane (scalar edge broadcast).
// Projections: persistent grid-stride, W staged once per block, per-wave
// 8-node tiles in private LDS slices (no block sync in the loop).
// xp,h bf16; edata packed u32 = src(16b) | bf16(ew). Assumes N<=65536, deg<256.
// ---------------------------------------------------------------------------

#define BUK 128              // nodes per bucket
#define BUK_SHIFT 7
#define FSH 256              // pass-1 edge slices (count/place blocks)
#define SS 128               // src-histogram slices
#define HIST_BS 512
#define NBUK_MAX 512
#define MAX_LDS_BYTES 131072
#define PROJ_GRID 512

#define SCAN_BS 256
#define SCAN_ITEMS 4
#define SCAN_CHUNK (SCAN_BS * SCAN_ITEMS)

__device__ __forceinline__ unsigned short f2bf(float f) {
    unsigned u = __float_as_uint(f);
    return (unsigned short)((u + 0x7fffu + ((u >> 16) & 1u)) >> 16);  // RNE
}
__device__ __forceinline__ float bf2f(unsigned short h) {
    return __uint_as_float((unsigned)h << 16);
}

// ---- shared gather core: cooperative edata load + readlane broadcast ---------
__device__ __forceinline__ float edge_gather(const int* __restrict__ offsets,
                                             const unsigned* __restrict__ edata,
                                             const unsigned short* __restrict__ xp,
                                             int n, int lane) {
    int beg = offsets[n];
    int end = offsets[n + 1];
    float a0 = 0.f, a1 = 0.f, a2 = 0.f, a3 = 0.f;
    for (int p = beg; p < end; p += 64) {
        int cnt = min(64, end - p);
        unsigned eb = (p + lane < end) ? edata[p + lane] : 0u;
        int k = 0;
        for (; k + 7 < cnt; k += 8) {
            unsigned e0 = __builtin_amdgcn_readlane(eb, k);
            unsigned e1 = __builtin_amdgcn_readlane(eb, k + 1);
            unsigned e2 = __builtin_amdgcn_readlane(eb, k + 2);
            unsigned e3 = __builtin_amdgcn_readlane(eb, k + 3);
            unsigned e4 = __builtin_amdgcn_readlane(eb, k + 4);
            unsigned e5 = __builtin_amdgcn_readlane(eb, k + 5);
            unsigned e6 = __builtin_amdgcn_readlane(eb, k + 6);
            unsigned e7 = __builtin_amdgcn_readlane(eb, k + 7);
            float v0 = bf2f(xp[(size_t)(e0 & 0xffffu) * 64 + lane]);
            float v1 = bf2f(xp[(size_t)(e1 & 0xffffu) * 64 + lane]);
            float v2 = bf2f(xp[(size_t)(e2 & 0xffffu) * 64 + lane]);
            float v3 = bf2f(xp[(size_t)(e3 & 0xffffu) * 64 + lane]);
            float v4 = bf2f(xp[(size_t)(e4 & 0xffffu) * 64 + lane]);
            float v5 = bf2f(xp[(size_t)(e5 & 0xffffu) * 64 + lane]);
            float v6 = bf2f(xp[(size_t)(e6 & 0xffffu) * 64 + lane]);
            float v7 = bf2f(xp[(size_t)(e7 & 0xffffu) * 64 + lane]);
            a0 = fmaf(v0, bf2f((unsigned short)(e0 >> 16)), a0);
            a1 = fmaf(v1, bf2f((unsigned short)(e1 >> 16)), a1);
            a2 = fmaf(v2, bf2f((unsigned short)(e2 >> 16)), a2);
            a3 = fmaf(v3, bf2f((unsigned short)(e3 >> 16)), a3);
            a0 = fmaf(v4, bf2f((unsigned short)(e4 >> 16)), a0);
            a1 = fmaf(v5, bf2f((unsigned short)(e5 >> 16)), a1);
            a2 = fmaf(v6, bf2f((unsigned short)(e6 >> 16)), a2);
            a3 = fmaf(v7, bf2f((unsigned short)(e7 >> 16)), a3);
        }
        for (; k < cnt; ++k) {
            unsigned e0 = __builtin_amdgcn_readlane(eb, k);
            a0 = fmaf(bf2f(xp[(size_t)(e0 & 0xffffu) * 64 + lane]),
                      bf2f((unsigned short)(e0 >> 16)), a0);
        }
    }
    return (a0 + a1) + (a2 + a3);
}

// ---- src out-degree histogram: per-slice packed u8 counts over N bins --------
__global__ void hist_src_kernel(const int* __restrict__ src, unsigned* __restrict__ partial_s,
                                int E, int NW4, int sliceS) {
    extern __shared__ unsigned h[];
    for (int i = threadIdx.x; i < NW4; i += blockDim.x) h[i] = 0u;
    __syncthreads();
    int s = blockIdx.x;
    int beg = s * sliceS, end = min(beg + sliceS, E);
    for (int e = beg + (int)threadIdx.x; e < end; e += blockDim.x) {
        int v = src[e];
        atomicAdd(&h[v >> 2], 1u << (8 * (v & 3)));
    }
    __syncthreads();
    unsigned* o = partial_s + (size_t)s * NW4;
    for (int i = threadIdx.x; i < NW4; i += blockDim.x) o[i] = h[i];
}

__global__ void reduce_src_kernel(const unsigned* __restrict__ partial_s,
                                  float* __restrict__ srcn, int N, int NW4) {
    int w = blockIdx.x * blockDim.x + threadIdx.x;
    if (w >= NW4) return;
    unsigned run = 0;
#pragma unroll 4
    for (int s = 0; s < SS; ++s) run += partial_s[(size_t)s * NW4 + w];
    int n0 = 4 * w;
#pragma unroll
    for (int k = 0; k < 4; ++k) {
        int n = n0 + k;
        if (n < N) srcn[n] = rsqrtf(fmaxf((float)((run >> (8 * k)) & 0xffu), 1.0f));
    }
}

// ---- per-slice bucket counts: cntmat[b*FSH + s] -------------------------------
__global__ void count_kernel(const int* __restrict__ dst, int* __restrict__ cntmat,
                             int E, int L, int NBUK) {
    __shared__ int c[NBUK_MAX];
    for (int i = threadIdx.x; i < NBUK; i += blockDim.x) c[i] = 0;
    __syncthreads();
    int s = blockIdx.x;
    int beg = s * L, end = min(beg + L, E);
    for (int e = beg + (int)threadIdx.x; e < end; e += blockDim.x)
        atomicAdd(&c[dst[e] >> BUK_SHIFT], 1);
    __syncthreads();
    for (int b = threadIdx.x; b < NBUK; b += blockDim.x)
        cntmat[(size_t)b * FSH + s] = c[b];
}

// ---- 3-kernel exclusive scan (generic, in-place capable) ----------------------
__global__ void scan_partial(const int* __restrict__ deg, int* __restrict__ bsum, int N) {
    __shared__ int sdata[SCAN_BS];
    int t = threadIdx.x;
    int base = blockIdx.x * SCAN_CHUNK + t * SCAN_ITEMS;
    int s = 0;
#pragma unroll
    for (int k = 0; k < SCAN_ITEMS; ++k) {
        int idx = base + k;
        s += (idx < N) ? deg[idx] : 0;
    }
    sdata[t] = s;
    __syncthreads();
    for (int off = SCAN_BS / 2; off > 0; off >>= 1) {
        if (t < off) sdata[t] += sdata[t + off];
        __syncthreads();
    }
    if (t == 0) bsum[blockIdx.x] = sdata[0];
}

__global__ void scan_bsums(int* __restrict__ bsum, int NB) {
    int carry = 0;
    for (int base = 0; base < NB; base += 64) {
        int l = base + (int)threadIdx.x;
        int v = (l < NB) ? bsum[l] : 0;
        int inc = v;
#pragma unroll
        for (int off = 1; off < 64; off <<= 1) {
            int tv = __shfl_up(inc, off, 64);
            if ((int)threadIdx.x >= off) inc += tv;
        }
        if (l < NB) bsum[l] = carry + inc - v;  // exclusive
        carry += __shfl(inc, 63, 64);
    }
}

__global__ void scan_final(const int* __restrict__ deg, const int* __restrict__ bsum,
                           int* __restrict__ offsets, int N) {
    __shared__ int sdata[SCAN_BS];
    int t = threadIdx.x;
    int base = blockIdx.x * SCAN_CHUNK + t * SCAN_ITEMS;
    int loc[SCAN_ITEMS];
    int s = 0;
#pragma unroll
    for (int k = 0; k < SCAN_ITEMS; ++k) {
        int idx = base + k;
        loc[k] = (idx < N) ? deg[idx] : 0;
        s += loc[k];
    }
    sdata[t] = s;
    __syncthreads();
    for (int off = 1; off < SCAN_BS; off <<= 1) {
        int v = (t >= off) ? sdata[t - off] : 0;
        __syncthreads();
        sdata[t] += v;
        __syncthreads();
    }
    int excl = sdata[t] - s + bsum[blockIdx.x];
#pragma unroll
    for (int k = 0; k < SCAN_ITEMS; ++k) {
        int idx = base + k;
        if (idx < N) {
            offsets[idx] = excl;
            if (idx == N - 1) offsets[N] = excl + loc[k];
        }
        excl += loc[k];
    }
}

// ---- pass 1: bin edges into per-(bucket,slice) contiguous segments ------------
__global__ void place_seg_kernel(const int* __restrict__ src, const int* __restrict__ dst,
                                 const float* __restrict__ ew, const int* __restrict__ cscan,
                                 uint2* __restrict__ inter, int E, int L, int NBUK) {
    __shared__ int cur[NBUK_MAX];
    int s = blockIdx.x;
    for (int b = threadIdx.x; b < NBUK; b += blockDim.x)
        cur[b] = cscan[(size_t)b * FSH + s];
    __syncthreads();
    int beg = s * L, end = min(beg + L, E);
    for (int e = beg + (int)threadIdx.x; e < end; e += blockDim.x) {
        int d = dst[e];
        int b = d >> BUK_SHIFT;
        int pos = atomicAdd(&cur[b], 1);
        inter[pos] = make_uint2((unsigned)src[e] | ((unsigned)f2bf(ew[e]) << 16),
                                (unsigned)(d & (BUK - 1)));
    }
}

// ---- pass 2: one block per bucket -> local degrees, offsets, dstn, final edata -
__global__ void fill_final_kernel(const uint2* __restrict__ inter,
                                  const int* __restrict__ cscan,
                                  unsigned* __restrict__ edata, int* __restrict__ offsets,
                                  float* __restrict__ dstn, int N, int NBUK) {
    __shared__ int cnt[BUK];
    __shared__ int loff[BUK];
    int b = blockIdx.x;
    int t = threadIdx.x;
    int beg = cscan[(size_t)b * FSH];
    int end = cscan[(size_t)(b + 1) * FSH];
    if (t < BUK) cnt[t] = 0;
    __syncthreads();
    for (int p = beg + t; p < end; p += blockDim.x)
        atomicAdd(&cnt[inter[p].y], 1);
    __syncthreads();
    if (t < 64) {
        int carry = 0;
#pragma unroll
        for (int base = 0; base < BUK; base += 64) {
            int v = cnt[base + t];
            int inc = v;
#pragma unroll
            for (int off = 1; off < 64; off <<= 1) {
                int tv = __shfl_up(inc, off, 64);
                if (t >= off) inc += tv;
            }
            loff[base + t] = carry + inc - v;
            carry += __shfl(inc, 63, 64);
        }
    }
    __syncthreads();
    int node0 = b << BUK_SHIFT;
    if (t < BUK) {
        int n = node0 + t;
        if (n < N) {
            offsets[n] = beg + loff[t];
            dstn[n] = rsqrtf(fmaxf((float)cnt[t], 1.0f));
        }
    }
    if (b == NBUK - 1 && t == 0) offsets[N] = end;
    __syncthreads();
    if (t < BUK) cnt[t] = 0;
    __syncthreads();
    for (int p = beg + t; p < end; p += blockDim.x) {
        uint2 r = inter[p];
        int dl = (int)r.y;
        int rk = atomicAdd(&cnt[dl], 1);
        edata[beg + loff[dl] + rk] = r.x;
    }
}

// ---- proj1: persistent grid-stride, W1 staged once, per-wave 8-node tiles -----
__global__ void __launch_bounds__(256, 8)
proj1_kernel(const float* __restrict__ X, const float* __restrict__ W1,
             const float* __restrict__ srcn, unsigned short* __restrict__ xp, int N) {
    __shared__ float w[32 * 64];       // 8 KB, staged once
    __shared__ float xs[4][8][32];     // 4 KB, per-wave slices
    int tid = threadIdx.x;
    {
        const float4* Wv = (const float4*)W1;
        float4* wv = (float4*)w;
        for (int i = tid; i < 32 * 64 / 4; i += 256) wv[i] = Wv[i];
    }
    __syncthreads();
    int lane = tid & 63;
    int wid = tid >> 6;
    int groups = (N + 7) >> 3;
    for (int g = blockIdx.x * 4 + wid; g < groups; g += gridDim.x * 4) {
        int n0 = g << 3;
        int nrem = min(8, N - n0);
        if (nrem == 8) {
            float4 v = ((const float4*)(X + (size_t)n0 * 32))[lane];
            *(float4*)&xs[wid][lane >> 3][(lane & 7) * 4] = v;
        } else {
            for (int i = lane; i < nrem * 32; i += 64)
                xs[wid][i >> 5][i & 31] = X[(size_t)n0 * 32 + i];
        }
        __asm__ volatile("s_waitcnt lgkmcnt(0)" ::: "memory");
        float acc[8] = {0.f, 0.f, 0.f, 0.f, 0.f, 0.f, 0.f, 0.f};
#pragma unroll
        for (int kk = 0; kk < 32; kk += 4) {
            float w0 = w[(kk + 0) * 64 + lane], w1 = w[(kk + 1) * 64 + lane];
            float w2 = w[(kk + 2) * 64 + lane], w3 = w[(kk + 3) * 64 + lane];
#pragma unroll
            for (int m = 0; m < 8; ++m) {
                float4 x = *(const float4*)&xs[wid][m][kk];
                acc[m] = fmaf(x.x, w0, fmaf(x.y, w1, fmaf(x.z, w2, fmaf(x.w, w3, acc[m]))));
            }
        }
#pragma unroll
        for (int m = 0; m < 8; ++m) {
            int n = n0 + m;
            if (n < N) xp[(size_t)n * 64 + lane] = f2bf(acc[m] * srcn[n]);
        }
    }
}

// ---- gather layer-1: segment-sum + relu/bias/dstn -> h (bf16) ------------------
__global__ void __launch_bounds__(256, 8)
gather_h_kernel(const int* __restrict__ offsets, const unsigned* __restrict__ edata,
                const unsigned short* __restrict__ xp, const float* __restrict__ dstn,
                const float* __restrict__ b1, unsigned short* __restrict__ hout, int N) {
    int lane = threadIdx.x & 63;
    int n = blockIdx.x * 4 + (threadIdx.x >> 6);
    if (n >= N) return;
    float acc = edge_gather(offsets, edata, xp, n, lane);
    float v = fmaxf(acc * dstn[n] + b1[lane], 0.0f);
    hout[(size_t)n * 64 + lane] = f2bf(v);
}

// ---- proj2: persistent grid-stride, W2 staged once, per-wave 8-node tiles -----
__global__ void __launch_bounds__(256, 4)
proj2b_kernel(const unsigned short* __restrict__ h, const float* __restrict__ X,
              const float* __restrict__ W2, const float* __restrict__ srcn,
              unsigned short* __restrict__ xp2, int N) {
    __shared__ float w[96 * 64];       // 24 KB, staged once
    __shared__ float xs[4][8][96];     // 12 KB, per-wave slices
    int tid = threadIdx.x;
    {
        const float4* Wv = (const float4*)W2;
        float4* wv = (float4*)w;
        for (int i = tid; i < 96 * 64 / 4; i += 256) wv[i] = Wv[i];
    }
    __syncthreads();
    int lane = tid & 63;
    int wid = tid >> 6;
    int groups = (N + 7) >> 3;
    for (int g = blockIdx.x * 4 + wid; g < groups; g += gridDim.x * 4) {
        int n0 = g << 3;
        int nrem = min(8, N - n0);
        if (nrem == 8) {
            // 8 h-rows (bf16): lane loads uint4 = 8 bf16; row = lane/8, col0 = (lane%8)*8
            uint4 hv = ((const uint4*)(h + (size_t)n0 * 64))[lane];
            int r = lane >> 3, c0 = (lane & 7) * 8;
            xs[wid][r][c0 + 0] = bf2f((unsigned short)(hv.x & 0xffffu));
            xs[wid][r][c0 + 1] = bf2f((unsigned short)(hv.x >> 16));
            xs[wid][r][c0 + 2] = bf2f((unsigned short)(hv.y & 0xffffu));
            xs[wid][r][c0 + 3] = bf2f((unsigned short)(hv.y >> 16));
            xs[wid][r][c0 + 4] = bf2f((unsigned short)(hv.z & 0xffffu));
            xs[wid][r][c0 + 5] = bf2f((unsigned short)(hv.z >> 16));
            xs[wid][r][c0 + 6] = bf2f((unsigned short)(hv.w & 0xffffu));
            xs[wid][r][c0 + 7] = bf2f((unsigned short)(hv.w >> 16));
            // 8 X-rows: lane loads float4; row = lane/8, col0 = 64 + (lane%8)*4
            float4 xv = ((const float4*)(X + (size_t)n0 * 32))[lane];
            *(float4*)&xs[wid][lane >> 3][64 + (lane & 7) * 4] = xv;
        } else {
            for (int i = lane; i < nrem * 64; i += 64)
                xs[wid][i >> 6][i & 63] = bf2f(h[(size_t)n0 * 64 + i]);
            for (int i = lane; i < nrem * 32; i += 64)
                xs[wid][i >> 5][64 + (i & 31)] = X[(size_t)n0 * 32 + i];
        }
        __asm__ volatile("s_waitcnt lgkmcnt(0)" ::: "memory");
        float acc[8] = {0.f, 0.f, 0.f, 0.f, 0.f, 0.f, 0.f, 0.f};
#pragma unroll 6
        for (int kk = 0; kk < 96; kk += 4) {
            float w0 = w[(kk + 0) * 64 + lane], w1 = w[(kk + 1) * 64 + lane];
            float w2 = w[(kk + 2) * 64 + lane], w3 = w[(kk + 3) * 64 + lane];
#pragma unroll
            for (int m = 0; m < 8; ++m) {
                float4 x = *(const float4*)&xs[wid][m][kk];
                acc[m] = fmaf(x.x, w0, fmaf(x.y, w1, fmaf(x.z, w2, fmaf(x.w, w3, acc[m]))));
            }
        }
#pragma unroll
        for (int m = 0; m < 8; ++m) {
            int n = n0 + m;
            if (n < N) xp2[(size_t)n * 64 + lane] = f2bf(acc[m] * srcn[n]);
        }
    }
}

// ---- final gather: layer-2 segment-sum + relu/bias/dstn + l2norm -> out -------
__global__ void __launch_bounds__(256, 8)
gather_final_kernel(const int* __restrict__ offsets, const unsigned* __restrict__ edata,
                    const unsigned short* __restrict__ xp2, const float* __restrict__ dstn,
                    const float* __restrict__ b2, float* __restrict__ out, int N) {
    int lane = threadIdx.x & 63;
    int n = blockIdx.x * 4 + (threadIdx.x >> 6);
    if (n >= N) return;
    float acc = edge_gather(offsets, edata, xp2, n, lane);
    float v = fmaxf(acc * dstn[n] + b2[lane], 0.0f);
    float s = v * v;
#pragma unroll
    for (int off = 32; off >= 1; off >>= 1) s += __shfl_xor(s, off, 64);
    v = v / fmaxf(sqrtf(s), 1e-12f);
    out[(size_t)n * 64 + lane] = v;
}

// ---------------- fallback path (atomic scatter) ---------------------------------
__global__ void deg_kernel_i(const int* __restrict__ src, const int* __restrict__ dst,
                             int* __restrict__ degs, int* __restrict__ degd, int E) {
    int i = blockIdx.x * blockDim.x + threadIdx.x;
    if (i < E) {
        atomicAdd(&degs[src[i]], 1);
        atomicAdd(&degd[dst[i]], 1);
    }
}

__global__ void norm_kernel_i(const int* __restrict__ degs, const int* __restrict__ degd,
                              float* __restrict__ srcn, float* __restrict__ dstn, int N) {
    int i = blockIdx.x * blockDim.x + threadIdx.x;
    if (i < N) {
        srcn[i] = rsqrtf(fmaxf((float)degs[i], 1.0f));
        dstn[i] = rsqrtf(fmaxf((float)degd[i], 1.0f));
    }
}

// f32-h projection for fallback layer 2 (h stored f32 in d_out)
__global__ void __launch_bounds__(256, 4)
proj2f_kernel(const float* __restrict__ h, const float* __restrict__ X,
              const float* __restrict__ W2, const float* __restrict__ srcn,
              unsigned short* __restrict__ xp2, int N) {
    __shared__ float w[96 * 64];
    __shared__ float xs[4][8][96];
    int tid = threadIdx.x;
    {
        const float4* Wv = (const float4*)W2;
        float4* wv = (float4*)w;
        for (int i = tid; i < 96 * 64 / 4; i += 256) wv[i] = Wv[i];
    }
    __syncthreads();
    int lane = tid & 63;
    int wid = tid >> 6;
    int groups = (N + 7) >> 3;
    for (int g = blockIdx.x * 4 + wid; g < groups; g += gridDim.x * 4) {
        int n0 = g << 3;
        int nrem = min(8, N - n0);
        for (int i = lane; i < nrem * 64; i += 64)
            xs[wid][i >> 6][i & 63] = h[(size_t)n0 * 64 + i];
        for (int i = lane; i < nrem * 32; i += 64)
            xs[wid][i >> 5][64 + (i & 31)] = X[(size_t)n0 * 32 + i];
        __asm__ volatile("s_waitcnt lgkmcnt(0)" ::: "memory");
        float acc[8] = {0.f, 0.f, 0.f, 0.f, 0.f, 0.f, 0.f, 0.f};
#pragma unroll 6
        for (int kk = 0; kk < 96; kk += 4) {
            float w0 = w[(kk + 0) * 64 + lane], w1 = w[(kk + 1) * 64 + lane];
            float w2 = w[(kk + 2) * 64 + lane], w3 = w[(kk + 3) * 64 + lane];
#pragma unroll
            for (int m = 0; m < 8; ++m) {
                float4 x = *(const float4*)&xs[wid][m][kk];
                acc[m] = fmaf(x.x, w0, fmaf(x.y, w1, fmaf(x.z, w2, fmaf(x.w, w3, acc[m]))));
            }
        }
#pragma unroll
        for (int m = 0; m < 8; ++m) {
            int n = n0 + m;
            if (n < N) xp2[(size_t)n * 64 + lane] = f2bf(acc[m] * srcn[n]);
        }
    }
}

__global__ void scatter_kernel(const int* __restrict__ src, const int* __restrict__ dst,
                               const float* __restrict__ ew,
                               const unsigned short* __restrict__ xp,
                               float* __restrict__ acc, int E) {
    int total = E * 64;
    int stride = gridDim.x * blockDim.x;
    for (int i = blockIdx.x * blockDim.x + threadIdx.x; i < total; i += stride) {
        int e = i >> 6;
        int f = i & 63;
        int s = src[e];
        int d = dst[e];
        float v = bf2f(xp[(size_t)s * 64 + f]) * ew[e];
        atomicAdd(&acc[(size_t)d * 64 + f], v);
    }
}

__global__ void relu_bias_kernel(float* __restrict__ h, const float* __restrict__ dstn,
                                 const float* __restrict__ b, int N) {
    int i = blockIdx.x * blockDim.x + threadIdx.x;
    if (i < N * 64) {
        int n = i >> 6;
        int j = i & 63;
        h[i] = fmaxf(h[i] * dstn[n] + b[j], 0.0f);
    }
}

__global__ void finalize_kernel(float* __restrict__ out, const float* __restrict__ dstn,
                                const float* __restrict__ b, int N) {
    int i = blockIdx.x * blockDim.x + threadIdx.x;
    int n = i >> 6;
    int f = i & 63;
    if (n >= N) return;
    float v = fmaxf(out[(size_t)n * 64 + f] * dstn[n] + b[f], 0.0f);
    float s = v * v;
#pragma unroll
    for (int off = 32; off >= 1; off >>= 1) s += __shfl_xor(s, off, 64);
    out[(size_t)n * 64 + f] = v / fmaxf(sqrtf(s), 1e-12f);
}

// ---------------------------------------------------------------------------

extern "C" void kernel_launch(void* const* d_in, const int* in_sizes, int n_in,
                              void* d_out, int out_size, void* d_ws, size_t ws_size,
                              hipStream_t stream) {
    const float* X   = (const float*)d_in[0];   // [N,32]
    const float* ew  = (const float*)d_in[1];   // [E,1]
    const int*   src = (const int*)d_in[2];     // [E]
    const int*   dst = (const int*)d_in[3];     // [E]
    const float* W1  = (const float*)d_in[4];   // [32,64]
    const float* b1  = (const float*)d_in[5];   // [64]
    const float* W2  = (const float*)d_in[6];   // [96,64]
    const float* b2  = (const float*)d_in[7];   // [64]

    const int N = in_sizes[0] / 32;
    const int E = in_sizes[2];
    const int NW4 = (N + 3) / 4;                  // packed u8 quads (src hist)
    const int NBUK = (N + BUK - 1) / BUK;         // 128-node buckets
    const int M = NBUK * FSH;                     // count-matrix size
    const int L = (E + FSH - 1) / FSH;            // edges per pass-1 slice
    const int sliceS = (E + SS - 1) / SS;
    const int NBscan = (M + SCAN_CHUNK - 1) / SCAN_CHUNK;

    float* out = (float*)d_out;
    char* wsb = (char*)d_ws;

    // region I aliasing, in stream order:
    //   partial_s[SS*NW4 u32] -> inter[E uint2] -> { xp[N*64 bf16] | h[N*64 bf16] }
    size_t o = 0;
    auto alloc = [&](size_t bytes) { size_t p = o; o += (bytes + 255) & ~(size_t)255; return p; };
    size_t szPS = (size_t)SS * NW4 * 4;
    size_t szIN = (size_t)E * 8;
    size_t szXP = ((size_t)N * 64 * 2 + 255) & ~(size_t)255;
    size_t szH  = (size_t)N * 64 * 2;
    size_t szI = szPS > szIN ? szPS : szIN;
    if (szXP + szH > szI) szI = szXP + szH;
    size_t offI    = alloc(szI);
    size_t offEd   = alloc((size_t)E * 4);
    size_t offXP2  = alloc((size_t)N * 64 * 2);
    size_t offCS   = alloc(((size_t)M + 1) * 4);
    size_t offSrcn = alloc((size_t)N * 4);
    size_t offDstn = alloc((size_t)N * 4);
    size_t offOff  = alloc(((size_t)N + 1) * 4);
    size_t offBsum = alloc((size_t)NBscan * 4);
    size_t need = o;

    // u8 src-hist requires per-node degree < 256; u16 src pack requires N<=65536.
    bool ok = (ws_size >= need) && (N <= 65536) && (NBUK <= NBUK_MAX) &&
              ((size_t)NW4 * 4 <= MAX_LDS_BYTES);

    if (ok) {
        unsigned*       partial_s = (unsigned*)(wsb + offI);
        uint2*          inter     = (uint2*)(wsb + offI);
        unsigned short* xp        = (unsigned short*)(wsb + offI);
        unsigned short* hbuf      = (unsigned short*)(wsb + offI + szXP);
        unsigned*       edata     = (unsigned*)(wsb + offEd);
        unsigned short* xp2       = (unsigned short*)(wsb + offXP2);
        int*            cscan     = (int*)(wsb + offCS);
        float*          srcn      = (float*)(wsb + offSrcn);
        float*          dstn      = (float*)(wsb + offDstn);
        int*            offsets   = (int*)(wsb + offOff);
        int*            bsum      = (int*)(wsb + offBsum);

        // srcn from u8 LDS histogram
        hist_src_kernel<<<SS, HIST_BS, (size_t)NW4 * 4, stream>>>(src, partial_s, E, NW4, sliceS);
        reduce_src_kernel<<<(NW4 + 255) / 256, 256, 0, stream>>>(partial_s, srcn, N, NW4);

        // two-pass bucket radix: count -> scan (in-place) -> place -> finalize
        count_kernel<<<FSH, HIST_BS, 0, stream>>>(dst, cscan, E, L, NBUK);
        scan_partial<<<NBscan, SCAN_BS, 0, stream>>>(cscan, bsum, M);
        scan_bsums<<<1, 64, 0, stream>>>(bsum, NBscan);
        scan_final<<<NBscan, SCAN_BS, 0, stream>>>(cscan, bsum, cscan, M);
        place_seg_kernel<<<FSH, HIST_BS, 0, stream>>>(src, dst, ew, cscan, inter, E, L, NBUK);
        fill_final_kernel<<<NBUK, 256, 0, stream>>>(inter, cscan, edata, offsets, dstn, N, NBUK);

        // layer 1: project -> gather (+relu/bias/dstn) -> h (bf16)
        proj1_kernel<<<PROJ_GRID, 256, 0, stream>>>(X, W1, srcn, xp, N);
        gather_h_kernel<<<(N + 3) / 4, 256, 0, stream>>>(offsets, edata, xp, dstn, b1, hbuf, N);
        // layer 2: project concat(h,X) -> gather (+relu/bias/dstn+l2norm) -> out
        proj2b_kernel<<<PROJ_GRID, 256, 0, stream>>>(hbuf, X, W2, srcn, xp2, N);
        gather_final_kernel<<<(N + 3) / 4, 256, 0, stream>>>(offsets, edata, xp2, dstn,
                                                             b2, out, N);
    } else {
        // fallback: atomic-scatter pipeline
        float* ws   = (float*)d_ws;
        int*   degs = (int*)ws;
        int*   degd = (int*)(ws + N);
        float* srcn = ws + 2 * (size_t)N;
        float* dstn = ws + 3 * (size_t)N;
        unsigned short* xp = (unsigned short*)(ws + 4 * (size_t)N);

        hipMemsetAsync(degs, 0, 2 * (size_t)N * sizeof(float), stream);
        hipMemsetAsync(out, 0, (size_t)N * 64 * sizeof(float), stream);

        deg_kernel_i<<<(E + 255) / 256, 256, 0, stream>>>(src, dst, degs, degd, E);
        norm_kernel_i<<<(N + 255) / 256, 256, 0, stream>>>(degs, degd, srcn, dstn, N);

        proj1_kernel<<<PROJ_GRID, 256, 0, stream>>>(X, W1, srcn, xp, N);
        scatter_kernel<<<2048, 256, 0, stream>>>(src, dst, ew, xp, out, E);
        relu_bias_kernel<<<(N * 64 + 255) / 256, 256, 0, stream>>>(out, dstn, b1, N);

        proj2f_kernel<<<PROJ_GRID, 256, 0, stream>>>(out, X, W2, srcn, xp, N);
        hipMemsetAsync(out, 0, (size_t)N * 64 * sizeof(float), stream);
        scatter_kernel<<<2048, 256, 0, stream>>>(src, dst, ew, xp, out, E);
        finalize_kernel<<<(N * 64 + 255) / 256, 256, 0, stream>>>(out, dstn, b2, N);
    }
}

// Round 12
// 267.928 us; speedup vs baseline: 1.1685x; 1.1685x over previous
//
#include <hip/hip_runtime.h>
#include <math.h>

// ---------------------------------------------------------------------------
// GCN via two-pass bucket radix (dst-grouped edges, zero global atomics).
// h1 = relu(dstn * S(ew * srcn*(X@W1)) + b1)
// h2 = relu(dstn * S(ew * srcn*([h1,X]@W2)) + b2) ; out = l2norm(h2)
// Gathers: cooperative edata load + v_readlane (scalar edge broadcast).
// Projections: persistent grid-stride, W staged once per block, per-wave
// 8-node tiles in private LDS slices. launch_bounds (256,4): (256,8) capped
// VGPRs at 32 -> acc[] spilled to scratch -> 537 MB HBM spill traffic (r11).
// xp,h bf16; edata packed u32 = src(16b) | bf16(ew). Assumes N<=65536, deg<256.
// ---------------------------------------------------------------------------

#define BUK 128              // nodes per bucket
#define BUK_SHIFT 7
#define FSH 256              // pass-1 edge slices (count/place blocks)
#define SS 128               // src-histogram slices
#define HIST_BS 512
#define NBUK_MAX 512
#define MAX_LDS_BYTES 131072
#define PROJ_GRID 512

#define SCAN_BS 256
#define SCAN_ITEMS 4
#define SCAN_CHUNK (SCAN_BS * SCAN_ITEMS)

__device__ __forceinline__ unsigned short f2bf(float f) {
    unsigned u = __float_as_uint(f);
    return (unsigned short)((u + 0x7fffu + ((u >> 16) & 1u)) >> 16);  // RNE
}
__device__ __forceinline__ float bf2f(unsigned short h) {
    return __uint_as_float((unsigned)h << 16);
}

// ---- shared gather core: cooperative edata load + readlane broadcast ---------
__device__ __forceinline__ float edge_gather(const int* __restrict__ offsets,
                                             const unsigned* __restrict__ edata,
                                             const unsigned short* __restrict__ xp,
                                             int n, int lane) {
    int beg = offsets[n];
    int end = offsets[n + 1];
    float a0 = 0.f, a1 = 0.f, a2 = 0.f, a3 = 0.f;
    for (int p = beg; p < end; p += 64) {
        int cnt = min(64, end - p);
        unsigned eb = (p + lane < end) ? edata[p + lane] : 0u;
        int k = 0;
        for (; k + 7 < cnt; k += 8) {
            unsigned e0 = __builtin_amdgcn_readlane(eb, k);
            unsigned e1 = __builtin_amdgcn_readlane(eb, k + 1);
            unsigned e2 = __builtin_amdgcn_readlane(eb, k + 2);
            unsigned e3 = __builtin_amdgcn_readlane(eb, k + 3);
            unsigned e4 = __builtin_amdgcn_readlane(eb, k + 4);
            unsigned e5 = __builtin_amdgcn_readlane(eb, k + 5);
            unsigned e6 = __builtin_amdgcn_readlane(eb, k + 6);
            unsigned e7 = __builtin_amdgcn_readlane(eb, k + 7);
            float v0 = bf2f(xp[(size_t)(e0 & 0xffffu) * 64 + lane]);
            float v1 = bf2f(xp[(size_t)(e1 & 0xffffu) * 64 + lane]);
            float v2 = bf2f(xp[(size_t)(e2 & 0xffffu) * 64 + lane]);
            float v3 = bf2f(xp[(size_t)(e3 & 0xffffu) * 64 + lane]);
            float v4 = bf2f(xp[(size_t)(e4 & 0xffffu) * 64 + lane]);
            float v5 = bf2f(xp[(size_t)(e5 & 0xffffu) * 64 + lane]);
            float v6 = bf2f(xp[(size_t)(e6 & 0xffffu) * 64 + lane]);
            float v7 = bf2f(xp[(size_t)(e7 & 0xffffu) * 64 + lane]);
            a0 = fmaf(v0, bf2f((unsigned short)(e0 >> 16)), a0);
            a1 = fmaf(v1, bf2f((unsigned short)(e1 >> 16)), a1);
            a2 = fmaf(v2, bf2f((unsigned short)(e2 >> 16)), a2);
            a3 = fmaf(v3, bf2f((unsigned short)(e3 >> 16)), a3);
            a0 = fmaf(v4, bf2f((unsigned short)(e4 >> 16)), a0);
            a1 = fmaf(v5, bf2f((unsigned short)(e5 >> 16)), a1);
            a2 = fmaf(v6, bf2f((unsigned short)(e6 >> 16)), a2);
            a3 = fmaf(v7, bf2f((unsigned short)(e7 >> 16)), a3);
        }
        for (; k < cnt; ++k) {
            unsigned e0 = __builtin_amdgcn_readlane(eb, k);
            a0 = fmaf(bf2f(xp[(size_t)(e0 & 0xffffu) * 64 + lane]),
                      bf2f((unsigned short)(e0 >> 16)), a0);
        }
    }
    return (a0 + a1) + (a2 + a3);
}

// ---- src out-degree histogram: per-slice packed u8 counts over N bins --------
__global__ void hist_src_kernel(const int* __restrict__ src, unsigned* __restrict__ partial_s,
                                int E, int NW4, int sliceS) {
    extern __shared__ unsigned h[];
    for (int i = threadIdx.x; i < NW4; i += blockDim.x) h[i] = 0u;
    __syncthreads();
    int s = blockIdx.x;
    int beg = s * sliceS, end = min(beg + sliceS, E);
    for (int e = beg + (int)threadIdx.x; e < end; e += blockDim.x) {
        int v = src[e];
        atomicAdd(&h[v >> 2], 1u << (8 * (v & 3)));
    }
    __syncthreads();
    unsigned* o = partial_s + (size_t)s * NW4;
    for (int i = threadIdx.x; i < NW4; i += blockDim.x) o[i] = h[i];
}

__global__ void reduce_src_kernel(const unsigned* __restrict__ partial_s,
                                  float* __restrict__ srcn, int N, int NW4) {
    int w = blockIdx.x * blockDim.x + threadIdx.x;
    if (w >= NW4) return;
    unsigned run = 0;
#pragma unroll 4
    for (int s = 0; s < SS; ++s) run += partial_s[(size_t)s * NW4 + w];
    int n0 = 4 * w;
#pragma unroll
    for (int k = 0; k < 4; ++k) {
        int n = n0 + k;
        if (n < N) srcn[n] = rsqrtf(fmaxf((float)((run >> (8 * k)) & 0xffu), 1.0f));
    }
}

// ---- per-slice bucket counts: cntmat[b*FSH + s] -------------------------------
__global__ void count_kernel(const int* __restrict__ dst, int* __restrict__ cntmat,
                             int E, int L, int NBUK) {
    __shared__ int c[NBUK_MAX];
    for (int i = threadIdx.x; i < NBUK; i += blockDim.x) c[i] = 0;
    __syncthreads();
    int s = blockIdx.x;
    int beg = s * L, end = min(beg + L, E);
    for (int e = beg + (int)threadIdx.x; e < end; e += blockDim.x)
        atomicAdd(&c[dst[e] >> BUK_SHIFT], 1);
    __syncthreads();
    for (int b = threadIdx.x; b < NBUK; b += blockDim.x)
        cntmat[(size_t)b * FSH + s] = c[b];
}

// ---- 3-kernel exclusive scan (generic, in-place capable) ----------------------
__global__ void scan_partial(const int* __restrict__ deg, int* __restrict__ bsum, int N) {
    __shared__ int sdata[SCAN_BS];
    int t = threadIdx.x;
    int base = blockIdx.x * SCAN_CHUNK + t * SCAN_ITEMS;
    int s = 0;
#pragma unroll
    for (int k = 0; k < SCAN_ITEMS; ++k) {
        int idx = base + k;
        s += (idx < N) ? deg[idx] : 0;
    }
    sdata[t] = s;
    __syncthreads();
    for (int off = SCAN_BS / 2; off > 0; off >>= 1) {
        if (t < off) sdata[t] += sdata[t + off];
        __syncthreads();
    }
    if (t == 0) bsum[blockIdx.x] = sdata[0];
}

__global__ void scan_bsums(int* __restrict__ bsum, int NB) {
    int carry = 0;
    for (int base = 0; base < NB; base += 64) {
        int l = base + (int)threadIdx.x;
        int v = (l < NB) ? bsum[l] : 0;
        int inc = v;
#pragma unroll
        for (int off = 1; off < 64; off <<= 1) {
            int tv = __shfl_up(inc, off, 64);
            if ((int)threadIdx.x >= off) inc += tv;
        }
        if (l < NB) bsum[l] = carry + inc - v;  // exclusive
        carry += __shfl(inc, 63, 64);
    }
}

__global__ void scan_final(const int* __restrict__ deg, const int* __restrict__ bsum,
                           int* __restrict__ offsets, int N) {
    __shared__ int sdata[SCAN_BS];
    int t = threadIdx.x;
    int base = blockIdx.x * SCAN_CHUNK + t * SCAN_ITEMS;
    int loc[SCAN_ITEMS];
    int s = 0;
#pragma unroll
    for (int k = 0; k < SCAN_ITEMS; ++k) {
        int idx = base + k;
        loc[k] = (idx < N) ? deg[idx] : 0;
        s += loc[k];
    }
    sdata[t] = s;
    __syncthreads();
    for (int off = 1; off < SCAN_BS; off <<= 1) {
        int v = (t >= off) ? sdata[t - off] : 0;
        __syncthreads();
        sdata[t] += v;
        __syncthreads();
    }
    int excl = sdata[t] - s + bsum[blockIdx.x];
#pragma unroll
    for (int k = 0; k < SCAN_ITEMS; ++k) {
        int idx = base + k;
        if (idx < N) {
            offsets[idx] = excl;
            if (idx == N - 1) offsets[N] = excl + loc[k];
        }
        excl += loc[k];
    }
}

// ---- pass 1: bin edges into per-(bucket,slice) contiguous segments ------------
__global__ void place_seg_kernel(const int* __restrict__ src, const int* __restrict__ dst,
                                 const float* __restrict__ ew, const int* __restrict__ cscan,
                                 uint2* __restrict__ inter, int E, int L, int NBUK) {
    __shared__ int cur[NBUK_MAX];
    int s = blockIdx.x;
    for (int b = threadIdx.x; b < NBUK; b += blockDim.x)
        cur[b] = cscan[(size_t)b * FSH + s];
    __syncthreads();
    int beg = s * L, end = min(beg + L, E);
    for (int e = beg + (int)threadIdx.x; e < end; e += blockDim.x) {
        int d = dst[e];
        int b = d >> BUK_SHIFT;
        int pos = atomicAdd(&cur[b], 1);
        inter[pos] = make_uint2((unsigned)src[e] | ((unsigned)f2bf(ew[e]) << 16),
                                (unsigned)(d & (BUK - 1)));
    }
}

// ---- pass 2: one block per bucket -> local degrees, offsets, dstn, final edata -
__global__ void fill_final_kernel(const uint2* __restrict__ inter,
                                  const int* __restrict__ cscan,
                                  unsigned* __restrict__ edata, int* __restrict__ offsets,
                                  float* __restrict__ dstn, int N, int NBUK) {
    __shared__ int cnt[BUK];
    __shared__ int loff[BUK];
    int b = blockIdx.x;
    int t = threadIdx.x;
    int beg = cscan[(size_t)b * FSH];
    int end = cscan[(size_t)(b + 1) * FSH];
    if (t < BUK) cnt[t] = 0;
    __syncthreads();
    for (int p = beg + t; p < end; p += blockDim.x)
        atomicAdd(&cnt[inter[p].y], 1);
    __syncthreads();
    if (t < 64) {
        int carry = 0;
#pragma unroll
        for (int base = 0; base < BUK; base += 64) {
            int v = cnt[base + t];
            int inc = v;
#pragma unroll
            for (int off = 1; off < 64; off <<= 1) {
                int tv = __shfl_up(inc, off, 64);
                if (t >= off) inc += tv;
            }
            loff[base + t] = carry + inc - v;
            carry += __shfl(inc, 63, 64);
        }
    }
    __syncthreads();
    int node0 = b << BUK_SHIFT;
    if (t < BUK) {
        int n = node0 + t;
        if (n < N) {
            offsets[n] = beg + loff[t];
            dstn[n] = rsqrtf(fmaxf((float)cnt[t], 1.0f));
        }
    }
    if (b == NBUK - 1 && t == 0) offsets[N] = end;
    __syncthreads();
    if (t < BUK) cnt[t] = 0;
    __syncthreads();
    for (int p = beg + t; p < end; p += blockDim.x) {
        uint2 r = inter[p];
        int dl = (int)r.y;
        int rk = atomicAdd(&cnt[dl], 1);
        edata[beg + loff[dl] + rk] = r.x;
    }
}

// ---- proj1: persistent grid-stride, W1 staged once, per-wave 8-node tiles -----
// launch_bounds (256,4): 128-VGPR budget — (256,8) forced 32 VGPRs and spilled.
__global__ void __launch_bounds__(256, 4)
proj1_kernel(const float* __restrict__ X, const float* __restrict__ W1,
             const float* __restrict__ srcn, unsigned short* __restrict__ xp, int N) {
    __shared__ float w[32 * 64];       // 8 KB, staged once
    __shared__ float xs[4][8][32];     // 4 KB, per-wave slices
    int tid = threadIdx.x;
    {
        const float4* Wv = (const float4*)W1;
        float4* wv = (float4*)w;
        for (int i = tid; i < 32 * 64 / 4; i += 256) wv[i] = Wv[i];
    }
    __syncthreads();
    int lane = tid & 63;
    int wid = tid >> 6;
    int groups = (N + 7) >> 3;
    for (int g = blockIdx.x * 4 + wid; g < groups; g += gridDim.x * 4) {
        int n0 = g << 3;
        int nrem = min(8, N - n0);
        if (nrem == 8) {
            float4 v = ((const float4*)(X + (size_t)n0 * 32))[lane];
            *(float4*)&xs[wid][lane >> 3][(lane & 7) * 4] = v;
        } else {
            for (int i = lane; i < nrem * 32; i += 64)
                xs[wid][i >> 5][i & 31] = X[(size_t)n0 * 32 + i];
        }
        __asm__ volatile("s_waitcnt lgkmcnt(0)" ::: "memory");
        float acc[8] = {0.f, 0.f, 0.f, 0.f, 0.f, 0.f, 0.f, 0.f};
#pragma unroll
        for (int kk = 0; kk < 32; kk += 4) {
            float w0 = w[(kk + 0) * 64 + lane], w1 = w[(kk + 1) * 64 + lane];
            float w2 = w[(kk + 2) * 64 + lane], w3 = w[(kk + 3) * 64 + lane];
#pragma unroll
            for (int m = 0; m < 8; ++m) {
                float4 x = *(const float4*)&xs[wid][m][kk];
                acc[m] = fmaf(x.x, w0, fmaf(x.y, w1, fmaf(x.z, w2, fmaf(x.w, w3, acc[m]))));
            }
        }
#pragma unroll
        for (int m = 0; m < 8; ++m) {
            int n = n0 + m;
            if (n < N) xp[(size_t)n * 64 + lane] = f2bf(acc[m] * srcn[n]);
        }
    }
}

// ---- gather layer-1: segment-sum + relu/bias/dstn -> h (bf16) ------------------
__global__ void __launch_bounds__(256, 8)
gather_h_kernel(const int* __restrict__ offsets, const unsigned* __restrict__ edata,
                const unsigned short* __restrict__ xp, const float* __restrict__ dstn,
                const float* __restrict__ b1, unsigned short* __restrict__ hout, int N) {
    int lane = threadIdx.x & 63;
    int n = blockIdx.x * 4 + (threadIdx.x >> 6);
    if (n >= N) return;
    float acc = edge_gather(offsets, edata, xp, n, lane);
    float v = fmaxf(acc * dstn[n] + b1[lane], 0.0f);
    hout[(size_t)n * 64 + lane] = f2bf(v);
}

// ---- proj2: persistent grid-stride, W2 staged once, per-wave 8-node tiles -----
__global__ void __launch_bounds__(256, 4)
proj2b_kernel(const unsigned short* __restrict__ h, const float* __restrict__ X,
              const float* __restrict__ W2, const float* __restrict__ srcn,
              unsigned short* __restrict__ xp2, int N) {
    __shared__ float w[96 * 64];       // 24 KB, staged once
    __shared__ float xs[4][8][96];     // 12 KB, per-wave slices
    int tid = threadIdx.x;
    {
        const float4* Wv = (const float4*)W2;
        float4* wv = (float4*)w;
        for (int i = tid; i < 96 * 64 / 4; i += 256) wv[i] = Wv[i];
    }
    __syncthreads();
    int lane = tid & 63;
    int wid = tid >> 6;
    int groups = (N + 7) >> 3;
    for (int g = blockIdx.x * 4 + wid; g < groups; g += gridDim.x * 4) {
        int n0 = g << 3;
        int nrem = min(8, N - n0);
        if (nrem == 8) {
            // 8 h-rows (bf16): lane loads uint4 = 8 bf16; row = lane/8, col0 = (lane%8)*8
            uint4 hv = ((const uint4*)(h + (size_t)n0 * 64))[lane];
            int r = lane >> 3, c0 = (lane & 7) * 8;
            xs[wid][r][c0 + 0] = bf2f((unsigned short)(hv.x & 0xffffu));
            xs[wid][r][c0 + 1] = bf2f((unsigned short)(hv.x >> 16));
            xs[wid][r][c0 + 2] = bf2f((unsigned short)(hv.y & 0xffffu));
            xs[wid][r][c0 + 3] = bf2f((unsigned short)(hv.y >> 16));
            xs[wid][r][c0 + 4] = bf2f((unsigned short)(hv.z & 0xffffu));
            xs[wid][r][c0 + 5] = bf2f((unsigned short)(hv.z >> 16));
            xs[wid][r][c0 + 6] = bf2f((unsigned short)(hv.w & 0xffffu));
            xs[wid][r][c0 + 7] = bf2f((unsigned short)(hv.w >> 16));
            // 8 X-rows: lane loads float4; row = lane/8, col0 = 64 + (lane%8)*4
            float4 xv = ((const float4*)(X + (size_t)n0 * 32))[lane];
            *(float4*)&xs[wid][lane >> 3][64 + (lane & 7) * 4] = xv;
        } else {
            for (int i = lane; i < nrem * 64; i += 64)
                xs[wid][i >> 6][i & 63] = bf2f(h[(size_t)n0 * 64 + i]);
            for (int i = lane; i < nrem * 32; i += 64)
                xs[wid][i >> 5][64 + (i & 31)] = X[(size_t)n0 * 32 + i];
        }
        __asm__ volatile("s_waitcnt lgkmcnt(0)" ::: "memory");
        float acc[8] = {0.f, 0.f, 0.f, 0.f, 0.f, 0.f, 0.f, 0.f};
#pragma unroll 6
        for (int kk = 0; kk < 96; kk += 4) {
            float w0 = w[(kk + 0) * 64 + lane], w1 = w[(kk + 1) * 64 + lane];
            float w2 = w[(kk + 2) * 64 + lane], w3 = w[(kk + 3) * 64 + lane];
#pragma unroll
            for (int m = 0; m < 8; ++m) {
                float4 x = *(const float4*)&xs[wid][m][kk];
                acc[m] = fmaf(x.x, w0, fmaf(x.y, w1, fmaf(x.z, w2, fmaf(x.w, w3, acc[m]))));
            }
        }
#pragma unroll
        for (int m = 0; m < 8; ++m) {
            int n = n0 + m;
            if (n < N) xp2[(size_t)n * 64 + lane] = f2bf(acc[m] * srcn[n]);
        }
    }
}

// ---- final gather: layer-2 segment-sum + relu/bias/dstn + l2norm -> out -------
__global__ void __launch_bounds__(256, 8)
gather_final_kernel(const int* __restrict__ offsets, const unsigned* __restrict__ edata,
                    const unsigned short* __restrict__ xp2, const float* __restrict__ dstn,
                    const float* __restrict__ b2, float* __restrict__ out, int N) {
    int lane = threadIdx.x & 63;
    int n = blockIdx.x * 4 + (threadIdx.x >> 6);
    if (n >= N) return;
    float acc = edge_gather(offsets, edata, xp2, n, lane);
    float v = fmaxf(acc * dstn[n] + b2[lane], 0.0f);
    float s = v * v;
#pragma unroll
    for (int off = 32; off >= 1; off >>= 1) s += __shfl_xor(s, off, 64);
    v = v / fmaxf(sqrtf(s), 1e-12f);
    out[(size_t)n * 64 + lane] = v;
}

// ---------------- fallback path (atomic scatter) ---------------------------------
__global__ void deg_kernel_i(const int* __restrict__ src, const int* __restrict__ dst,
                             int* __restrict__ degs, int* __restrict__ degd, int E) {
    int i = blockIdx.x * blockDim.x + threadIdx.x;
    if (i < E) {
        atomicAdd(&degs[src[i]], 1);
        atomicAdd(&degd[dst[i]], 1);
    }
}

__global__ void norm_kernel_i(const int* __restrict__ degs, const int* __restrict__ degd,
                              float* __restrict__ srcn, float* __restrict__ dstn, int N) {
    int i = blockIdx.x * blockDim.x + threadIdx.x;
    if (i < N) {
        srcn[i] = rsqrtf(fmaxf((float)degs[i], 1.0f));
        dstn[i] = rsqrtf(fmaxf((float)degd[i], 1.0f));
    }
}

// f32-h projection for fallback layer 2 (h stored f32 in d_out)
__global__ void __launch_bounds__(256, 4)
proj2f_kernel(const float* __restrict__ h, const float* __restrict__ X,
              const float* __restrict__ W2, const float* __restrict__ srcn,
              unsigned short* __restrict__ xp2, int N) {
    __shared__ float w[96 * 64];
    __shared__ float xs[4][8][96];
    int tid = threadIdx.x;
    {
        const float4* Wv = (const float4*)W2;
        float4* wv = (float4*)w;
        for (int i = tid; i < 96 * 64 / 4; i += 256) wv[i] = Wv[i];
    }
    __syncthreads();
    int lane = tid & 63;
    int wid = tid >> 6;
    int groups = (N + 7) >> 3;
    for (int g = blockIdx.x * 4 + wid; g < groups; g += gridDim.x * 4) {
        int n0 = g << 3;
        int nrem = min(8, N - n0);
        for (int i = lane; i < nrem * 64; i += 64)
            xs[wid][i >> 6][i & 63] = h[(size_t)n0 * 64 + i];
        for (int i = lane; i < nrem * 32; i += 64)
            xs[wid][i >> 5][64 + (i & 31)] = X[(size_t)n0 * 32 + i];
        __asm__ volatile("s_waitcnt lgkmcnt(0)" ::: "memory");
        float acc[8] = {0.f, 0.f, 0.f, 0.f, 0.f, 0.f, 0.f, 0.f};
#pragma unroll 6
        for (int kk = 0; kk < 96; kk += 4) {
            float w0 = w[(kk + 0) * 64 + lane], w1 = w[(kk + 1) * 64 + lane];
            float w2 = w[(kk + 2) * 64 + lane], w3 = w[(kk + 3) * 64 + lane];
#pragma unroll
            for (int m = 0; m < 8; ++m) {
                float4 x = *(const float4*)&xs[wid][m][kk];
                acc[m] = fmaf(x.x, w0, fmaf(x.y, w1, fmaf(x.z, w2, fmaf(x.w, w3, acc[m]))));
            }
        }
#pragma unroll
        for (int m = 0; m < 8; ++m) {
            int n = n0 + m;
            if (n < N) xp2[(size_t)n * 64 + lane] = f2bf(acc[m] * srcn[n]);
        }
    }
}

__global__ void scatter_kernel(const int* __restrict__ src, const int* __restrict__ dst,
                               const float* __restrict__ ew,
                               const unsigned short* __restrict__ xp,
                               float* __restrict__ acc, int E) {
    int total = E * 64;
    int stride = gridDim.x * blockDim.x;
    for (int i = blockIdx.x * blockDim.x + threadIdx.x; i < total; i += stride) {
        int e = i >> 6;
        int f = i & 63;
        int s = src[e];
        int d = dst[e];
        float v = bf2f(xp[(size_t)s * 64 + f]) * ew[e];
        atomicAdd(&acc[(size_t)d * 64 + f], v);
    }
}

__global__ void relu_bias_kernel(float* __restrict__ h, const float* __restrict__ dstn,
                                 const float* __restrict__ b, int N) {
    int i = blockIdx.x * blockDim.x + threadIdx.x;
    if (i < N * 64) {
        int n = i >> 6;
        int j = i & 63;
        h[i] = fmaxf(h[i] * dstn[n] + b[j], 0.0f);
    }
}

__global__ void finalize_kernel(float* __restrict__ out, const float* __restrict__ dstn,
                                const float* __restrict__ b, int N) {
    int i = blockIdx.x * blockDim.x + threadIdx.x;
    int n = i >> 6;
    int f = i & 63;
    if (n >= N) return;
    float v = fmaxf(out[(size_t)n * 64 + f] * dstn[n] + b[f], 0.0f);
    float s = v * v;
#pragma unroll
    for (int off = 32; off >= 1; off >>= 1) s += __shfl_xor(s, off, 64);
    out[(size_t)n * 64 + f] = v / fmaxf(sqrtf(s), 1e-12f);
}

// ---------------------------------------------------------------------------

extern "C" void kernel_launch(void* const* d_in, const int* in_sizes, int n_in,
                              void* d_out, int out_size, void* d_ws, size_t ws_size,
                              hipStream_t stream) {
    const float* X   = (const float*)d_in[0];   // [N,32]
    const float* ew  = (const float*)d_in[1];   // [E,1]
    const int*   src = (const int*)d_in[2];     // [E]
    const int*   dst = (const int*)d_in[3];     // [E]
    const float* W1  = (const float*)d_in[4];   // [32,64]
    const float* b1  = (const float*)d_in[5];   // [64]
    const float* W2  = (const float*)d_in[6];   // [96,64]
    const float* b2  = (const float*)d_in[7];   // [64]

    const int N = in_sizes[0] / 32;
    const int E = in_sizes[2];
    const int NW4 = (N + 3) / 4;                  // packed u8 quads (src hist)
    const int NBUK = (N + BUK - 1) / BUK;         // 128-node buckets
    const int M = NBUK * FSH;                     // count-matrix size
    const int L = (E + FSH - 1) / FSH;            // edges per pass-1 slice
    const int sliceS = (E + SS - 1) / SS;
    const int NBscan = (M + SCAN_CHUNK - 1) / SCAN_CHUNK;

    float* out = (float*)d_out;
    char* wsb = (char*)d_ws;

    // region I aliasing, in stream order:
    //   partial_s[SS*NW4 u32] -> inter[E uint2] -> { xp[N*64 bf16] | h[N*64 bf16] }
    size_t o = 0;
    auto alloc = [&](size_t bytes) { size_t p = o; o += (bytes + 255) & ~(size_t)255; return p; };
    size_t szPS = (size_t)SS * NW4 * 4;
    size_t szIN = (size_t)E * 8;
    size_t szXP = ((size_t)N * 64 * 2 + 255) & ~(size_t)255;
    size_t szH  = (size_t)N * 64 * 2;
    size_t szI = szPS > szIN ? szPS : szIN;
    if (szXP + szH > szI) szI = szXP + szH;
    size_t offI    = alloc(szI);
    size_t offEd   = alloc((size_t)E * 4);
    size_t offXP2  = alloc((size_t)N * 64 * 2);
    size_t offCS   = alloc(((size_t)M + 1) * 4);
    size_t offSrcn = alloc((size_t)N * 4);
    size_t offDstn = alloc((size_t)N * 4);
    size_t offOff  = alloc(((size_t)N + 1) * 4);
    size_t offBsum = alloc((size_t)NBscan * 4);
    size_t need = o;

    // u8 src-hist requires per-node degree < 256; u16 src pack requires N<=65536.
    bool ok = (ws_size >= need) && (N <= 65536) && (NBUK <= NBUK_MAX) &&
              ((size_t)NW4 * 4 <= MAX_LDS_BYTES);

    if (ok) {
        unsigned*       partial_s = (unsigned*)(wsb + offI);
        uint2*          inter     = (uint2*)(wsb + offI);
        unsigned short* xp        = (unsigned short*)(wsb + offI);
        unsigned short* hbuf      = (unsigned short*)(wsb + offI + szXP);
        unsigned*       edata     = (unsigned*)(wsb + offEd);
        unsigned short* xp2       = (unsigned short*)(wsb + offXP2);
        int*            cscan     = (int*)(wsb + offCS);
        float*          srcn      = (float*)(wsb + offSrcn);
        float*          dstn      = (float*)(wsb + offDstn);
        int*            offsets   = (int*)(wsb + offOff);
        int*            bsum      = (int*)(wsb + offBsum);

        // srcn from u8 LDS histogram
        hist_src_kernel<<<SS, HIST_BS, (size_t)NW4 * 4, stream>>>(src, partial_s, E, NW4, sliceS);
        reduce_src_kernel<<<(NW4 + 255) / 256, 256, 0, stream>>>(partial_s, srcn, N, NW4);

        // two-pass bucket radix: count -> scan (in-place) -> place -> finalize
        count_kernel<<<FSH, HIST_BS, 0, stream>>>(dst, cscan, E, L, NBUK);
        scan_partial<<<NBscan, SCAN_BS, 0, stream>>>(cscan, bsum, M);
        scan_bsums<<<1, 64, 0, stream>>>(bsum, NBscan);
        scan_final<<<NBscan, SCAN_BS, 0, stream>>>(cscan, bsum, cscan, M);
        place_seg_kernel<<<FSH, HIST_BS, 0, stream>>>(src, dst, ew, cscan, inter, E, L, NBUK);
        fill_final_kernel<<<NBUK, 256, 0, stream>>>(inter, cscan, edata, offsets, dstn, N, NBUK);

        // layer 1: project -> gather (+relu/bias/dstn) -> h (bf16)
        proj1_kernel<<<PROJ_GRID, 256, 0, stream>>>(X, W1, srcn, xp, N);
        gather_h_kernel<<<(N + 3) / 4, 256, 0, stream>>>(offsets, edata, xp, dstn, b1, hbuf, N);
        // layer 2: project concat(h,X) -> gather (+relu/bias/dstn+l2norm) -> out
        proj2b_kernel<<<PROJ_GRID, 256, 0, stream>>>(hbuf, X, W2, srcn, xp2, N);
        gather_final_kernel<<<(N + 3) / 4, 256, 0, stream>>>(offsets, edata, xp2, dstn,
                                                             b2, out, N);
    } else {
        // fallback: atomic-scatter pipeline
        float* ws   = (float*)d_ws;
        int*   degs = (int*)ws;
        int*   degd = (int*)(ws + N);
        float* srcn = ws + 2 * (size_t)N;
        float* dstn = ws + 3 * (size_t)N;
        unsigned short* xp = (unsigned short*)(ws + 4 * (size_t)N);

        hipMemsetAsync(degs, 0, 2 * (size_t)N * sizeof(float), stream);
        hipMemsetAsync(out, 0, (size_t)N * 64 * sizeof(float), stream);

        deg_kernel_i<<<(E + 255) / 256, 256, 0, stream>>>(src, dst, degs, degd, E);
        norm_kernel_i<<<(N + 255) / 256, 256, 0, stream>>>(degs, degd, srcn, dstn, N);

        proj1_kernel<<<PROJ_GRID, 256, 0, stream>>>(X, W1, srcn, xp, N);
        scatter_kernel<<<2048, 256, 0, stream>>>(src, dst, ew, xp, out, E);
        relu_bias_kernel<<<(N * 64 + 255) / 256, 256, 0, stream>>>(out, dstn, b1, N);

        proj2f_kernel<<<PROJ_GRID, 256, 0, stream>>>(out, X, W2, srcn, xp, N);
        hipMemsetAsync(out, 0, (size_t)N * 64 * sizeof(float), stream);
        scatter_kernel<<<2048, 256, 0, stream>>>(src, dst, ew, xp, out, E);
        finalize_kernel<<<(N * 64 + 255) / 256, 256, 0, stream>>>(out, dstn, b2, N);
    }
}

// Round 13
// 197.441 us; speedup vs baseline: 1.5856x; 1.3570x over previous
//
#include <hip/hip_runtime.h>
#include <math.h>

// ---------------------------------------------------------------------------
// GCN via two-pass bucket radix (dst-grouped edges, zero global atomics).
// h1 = relu(dstn * S(ew * srcn*(X@W1)) + b1)
// h2 = relu(dstn * S(ew * srcn*([h1,X]@W2)) + b2) ; out = l2norm(h2)
// Gathers: cooperative edata load + v_readlane (scalar edge broadcast).
// Projections: persistent blocks; W in LDS (staged once); node rows held in
// REGISTERS and broadcast per-k via v_readlane -> v_fmac. No LDS X-staging,
// no launch_bounds (r11/r12: bounds forced 32/64-VGPR caps -> scratch spill,
// 280-540 MB of HBM spill traffic), no inline asm.
// xp,h bf16; edata packed u32 = src(16b) | bf16(ew). Assumes N<=65536, deg<256.
// ---------------------------------------------------------------------------

#define BUK 128              // nodes per bucket
#define BUK_SHIFT 7
#define FSH 256              // pass-1 edge slices (count/place blocks)
#define SS 128               // src-histogram slices
#define HIST_BS 512
#define NBUK_MAX 512
#define MAX_LDS_BYTES 131072
#define PROJ_GRID 512

#define SCAN_BS 256
#define SCAN_ITEMS 4
#define SCAN_CHUNK (SCAN_BS * SCAN_ITEMS)

__device__ __forceinline__ unsigned short f2bf(float f) {
    unsigned u = __float_as_uint(f);
    return (unsigned short)((u + 0x7fffu + ((u >> 16) & 1u)) >> 16);  // RNE
}
__device__ __forceinline__ float bf2f(unsigned short h) {
    return __uint_as_float((unsigned)h << 16);
}
__device__ __forceinline__ float rlane(float v, int k) {
    return __uint_as_float(__builtin_amdgcn_readlane(__float_as_uint(v), k));
}

// ---- shared gather core: cooperative edata load + readlane broadcast ---------
__device__ __forceinline__ float edge_gather(const int* __restrict__ offsets,
                                             const unsigned* __restrict__ edata,
                                             const unsigned short* __restrict__ xp,
                                             int n, int lane) {
    int beg = offsets[n];
    int end = offsets[n + 1];
    float a0 = 0.f, a1 = 0.f, a2 = 0.f, a3 = 0.f;
    for (int p = beg; p < end; p += 64) {
        int cnt = min(64, end - p);
        unsigned eb = (p + lane < end) ? edata[p + lane] : 0u;
        int k = 0;
        for (; k + 7 < cnt; k += 8) {
            unsigned e0 = __builtin_amdgcn_readlane(eb, k);
            unsigned e1 = __builtin_amdgcn_readlane(eb, k + 1);
            unsigned e2 = __builtin_amdgcn_readlane(eb, k + 2);
            unsigned e3 = __builtin_amdgcn_readlane(eb, k + 3);
            unsigned e4 = __builtin_amdgcn_readlane(eb, k + 4);
            unsigned e5 = __builtin_amdgcn_readlane(eb, k + 5);
            unsigned e6 = __builtin_amdgcn_readlane(eb, k + 6);
            unsigned e7 = __builtin_amdgcn_readlane(eb, k + 7);
            float v0 = bf2f(xp[(size_t)(e0 & 0xffffu) * 64 + lane]);
            float v1 = bf2f(xp[(size_t)(e1 & 0xffffu) * 64 + lane]);
            float v2 = bf2f(xp[(size_t)(e2 & 0xffffu) * 64 + lane]);
            float v3 = bf2f(xp[(size_t)(e3 & 0xffffu) * 64 + lane]);
            float v4 = bf2f(xp[(size_t)(e4 & 0xffffu) * 64 + lane]);
            float v5 = bf2f(xp[(size_t)(e5 & 0xffffu) * 64 + lane]);
            float v6 = bf2f(xp[(size_t)(e6 & 0xffffu) * 64 + lane]);
            float v7 = bf2f(xp[(size_t)(e7 & 0xffffu) * 64 + lane]);
            a0 = fmaf(v0, bf2f((unsigned short)(e0 >> 16)), a0);
            a1 = fmaf(v1, bf2f((unsigned short)(e1 >> 16)), a1);
            a2 = fmaf(v2, bf2f((unsigned short)(e2 >> 16)), a2);
            a3 = fmaf(v3, bf2f((unsigned short)(e3 >> 16)), a3);
            a0 = fmaf(v4, bf2f((unsigned short)(e4 >> 16)), a0);
            a1 = fmaf(v5, bf2f((unsigned short)(e5 >> 16)), a1);
            a2 = fmaf(v6, bf2f((unsigned short)(e6 >> 16)), a2);
            a3 = fmaf(v7, bf2f((unsigned short)(e7 >> 16)), a3);
        }
        for (; k < cnt; ++k) {
            unsigned e0 = __builtin_amdgcn_readlane(eb, k);
            a0 = fmaf(bf2f(xp[(size_t)(e0 & 0xffffu) * 64 + lane]),
                      bf2f((unsigned short)(e0 >> 16)), a0);
        }
    }
    return (a0 + a1) + (a2 + a3);
}

// ---- src out-degree histogram: per-slice packed u8 counts over N bins --------
__global__ void hist_src_kernel(const int* __restrict__ src, unsigned* __restrict__ partial_s,
                                int E, int NW4, int sliceS) {
    extern __shared__ unsigned h[];
    for (int i = threadIdx.x; i < NW4; i += blockDim.x) h[i] = 0u;
    __syncthreads();
    int s = blockIdx.x;
    int beg = s * sliceS, end = min(beg + sliceS, E);
    for (int e = beg + (int)threadIdx.x; e < end; e += blockDim.x) {
        int v = src[e];
        atomicAdd(&h[v >> 2], 1u << (8 * (v & 3)));
    }
    __syncthreads();
    unsigned* o = partial_s + (size_t)s * NW4;
    for (int i = threadIdx.x; i < NW4; i += blockDim.x) o[i] = h[i];
}

__global__ void reduce_src_kernel(const unsigned* __restrict__ partial_s,
                                  float* __restrict__ srcn, int N, int NW4) {
    int w = blockIdx.x * blockDim.x + threadIdx.x;
    if (w >= NW4) return;
    unsigned run = 0;
#pragma unroll 4
    for (int s = 0; s < SS; ++s) run += partial_s[(size_t)s * NW4 + w];
    int n0 = 4 * w;
#pragma unroll
    for (int k = 0; k < 4; ++k) {
        int n = n0 + k;
        if (n < N) srcn[n] = rsqrtf(fmaxf((float)((run >> (8 * k)) & 0xffu), 1.0f));
    }
}

// ---- per-slice bucket counts: cntmat[b*FSH + s] -------------------------------
__global__ void count_kernel(const int* __restrict__ dst, int* __restrict__ cntmat,
                             int E, int L, int NBUK) {
    __shared__ int c[NBUK_MAX];
    for (int i = threadIdx.x; i < NBUK; i += blockDim.x) c[i] = 0;
    __syncthreads();
    int s = blockIdx.x;
    int beg = s * L, end = min(beg + L, E);
    for (int e = beg + (int)threadIdx.x; e < end; e += blockDim.x)
        atomicAdd(&c[dst[e] >> BUK_SHIFT], 1);
    __syncthreads();
    for (int b = threadIdx.x; b < NBUK; b += blockDim.x)
        cntmat[(size_t)b * FSH + s] = c[b];
}

// ---- 3-kernel exclusive scan (generic, in-place capable) ----------------------
__global__ void scan_partial(const int* __restrict__ deg, int* __restrict__ bsum, int N) {
    __shared__ int sdata[SCAN_BS];
    int t = threadIdx.x;
    int base = blockIdx.x * SCAN_CHUNK + t * SCAN_ITEMS;
    int s = 0;
#pragma unroll
    for (int k = 0; k < SCAN_ITEMS; ++k) {
        int idx = base + k;
        s += (idx < N) ? deg[idx] : 0;
    }
    sdata[t] = s;
    __syncthreads();
    for (int off = SCAN_BS / 2; off > 0; off >>= 1) {
        if (t < off) sdata[t] += sdata[t + off];
        __syncthreads();
    }
    if (t == 0) bsum[blockIdx.x] = sdata[0];
}

__global__ void scan_bsums(int* __restrict__ bsum, int NB) {
    int carry = 0;
    for (int base = 0; base < NB; base += 64) {
        int l = base + (int)threadIdx.x;
        int v = (l < NB) ? bsum[l] : 0;
        int inc = v;
#pragma unroll
        for (int off = 1; off < 64; off <<= 1) {
            int tv = __shfl_up(inc, off, 64);
            if ((int)threadIdx.x >= off) inc += tv;
        }
        if (l < NB) bsum[l] = carry + inc - v;  // exclusive
        carry += __shfl(inc, 63, 64);
    }
}

__global__ void scan_final(const int* __restrict__ deg, const int* __restrict__ bsum,
                           int* __restrict__ offsets, int N) {
    __shared__ int sdata[SCAN_BS];
    int t = threadIdx.x;
    int base = blockIdx.x * SCAN_CHUNK + t * SCAN_ITEMS;
    int loc[SCAN_ITEMS];
    int s = 0;
#pragma unroll
    for (int k = 0; k < SCAN_ITEMS; ++k) {
        int idx = base + k;
        loc[k] = (idx < N) ? deg[idx] : 0;
        s += loc[k];
    }
    sdata[t] = s;
    __syncthreads();
    for (int off = 1; off < SCAN_BS; off <<= 1) {
        int v = (t >= off) ? sdata[t - off] : 0;
        __syncthreads();
        sdata[t] += v;
        __syncthreads();
    }
    int excl = sdata[t] - s + bsum[blockIdx.x];
#pragma unroll
    for (int k = 0; k < SCAN_ITEMS; ++k) {
        int idx = base + k;
        if (idx < N) {
            offsets[idx] = excl;
            if (idx == N - 1) offsets[N] = excl + loc[k];
        }
        excl += loc[k];
    }
}

// ---- pass 1: bin edges into per-(bucket,slice) contiguous segments ------------
__global__ void place_seg_kernel(const int* __restrict__ src, const int* __restrict__ dst,
                                 const float* __restrict__ ew, const int* __restrict__ cscan,
                                 uint2* __restrict__ inter, int E, int L, int NBUK) {
    __shared__ int cur[NBUK_MAX];
    int s = blockIdx.x;
    for (int b = threadIdx.x; b < NBUK; b += blockDim.x)
        cur[b] = cscan[(size_t)b * FSH + s];
    __syncthreads();
    int beg = s * L, end = min(beg + L, E);
    for (int e = beg + (int)threadIdx.x; e < end; e += blockDim.x) {
        int d = dst[e];
        int b = d >> BUK_SHIFT;
        int pos = atomicAdd(&cur[b], 1);
        inter[pos] = make_uint2((unsigned)src[e] | ((unsigned)f2bf(ew[e]) << 16),
                                (unsigned)(d & (BUK - 1)));
    }
}

// ---- pass 2: one block per bucket -> local degrees, offsets, dstn, final edata -
__global__ void fill_final_kernel(const uint2* __restrict__ inter,
                                  const int* __restrict__ cscan,
                                  unsigned* __restrict__ edata, int* __restrict__ offsets,
                                  float* __restrict__ dstn, int N, int NBUK) {
    __shared__ int cnt[BUK];
    __shared__ int loff[BUK];
    int b = blockIdx.x;
    int t = threadIdx.x;
    int beg = cscan[(size_t)b * FSH];
    int end = cscan[(size_t)(b + 1) * FSH];
    if (t < BUK) cnt[t] = 0;
    __syncthreads();
    for (int p = beg + t; p < end; p += blockDim.x)
        atomicAdd(&cnt[inter[p].y], 1);
    __syncthreads();
    if (t < 64) {
        int carry = 0;
#pragma unroll
        for (int base = 0; base < BUK; base += 64) {
            int v = cnt[base + t];
            int inc = v;
#pragma unroll
            for (int off = 1; off < 64; off <<= 1) {
                int tv = __shfl_up(inc, off, 64);
                if (t >= off) inc += tv;
            }
            loff[base + t] = carry + inc - v;
            carry += __shfl(inc, 63, 64);
        }
    }
    __syncthreads();
    int node0 = b << BUK_SHIFT;
    if (t < BUK) {
        int n = node0 + t;
        if (n < N) {
            offsets[n] = beg + loff[t];
            dstn[n] = rsqrtf(fmaxf((float)cnt[t], 1.0f));
        }
    }
    if (b == NBUK - 1 && t == 0) offsets[N] = end;
    __syncthreads();
    if (t < BUK) cnt[t] = 0;
    __syncthreads();
    for (int p = beg + t; p < end; p += blockDim.x) {
        uint2 r = inter[p];
        int dl = (int)r.y;
        int rk = atomicAdd(&cnt[dl], 1);
        edata[beg + loff[dl] + rk] = r.x;
    }
}

// ---- proj1: persistent; W1 in LDS; 16 nodes/wave in regs; readlane broadcast --
__global__ void proj1_kernel(const float* __restrict__ X, const float* __restrict__ W1,
                             const float* __restrict__ srcn,
                             unsigned short* __restrict__ xp, int N) {
    __shared__ float w[32 * 64];       // 8 KB, staged once
    int tid = threadIdx.x;
    {
        const float4* Wv = (const float4*)W1;
        float4* wv = (float4*)w;
        for (int i = tid; i < 512; i += 256) wv[i] = Wv[i];
    }
    __syncthreads();
    int lane = tid & 63;
    int wid = tid >> 6;
    int half = lane >> 5;              // 0: even node of pair, 1: odd node
    int col = lane & 31;
    int nt = (N + 15) >> 4;            // 16-node tiles
    for (int t = blockIdx.x * 4 + wid; t < nt; t += gridDim.x * 4) {
        int n0 = t << 4;
        float xv[8];                   // xv[m]: lane<32 -> X[n0+2m][col], lane>=32 -> X[n0+2m+1][col]
        if (n0 + 16 <= N) {
#pragma unroll
            for (int m = 0; m < 8; ++m)
                xv[m] = X[(size_t)(n0 + 2 * m + half) * 32 + col];
        } else {
#pragma unroll
            for (int m = 0; m < 8; ++m) {
                int n = n0 + 2 * m + half;
                xv[m] = (n < N) ? X[(size_t)n * 32 + col] : 0.f;
            }
        }
        float acc[16];
#pragma unroll
        for (int i = 0; i < 16; ++i) acc[i] = 0.f;
#pragma unroll 8
        for (int k = 0; k < 32; ++k) {
            float wk = w[k * 64 + lane];
#pragma unroll
            for (int m = 0; m < 8; ++m) {
                acc[2 * m]     = fmaf(rlane(xv[m], k), wk, acc[2 * m]);
                acc[2 * m + 1] = fmaf(rlane(xv[m], 32 + k), wk, acc[2 * m + 1]);
            }
        }
#pragma unroll
        for (int i = 0; i < 16; ++i) {
            int n = n0 + i;
            if (n < N) xp[(size_t)n * 64 + lane] = f2bf(acc[i] * srcn[n]);
        }
    }
}

// ---- gather layer-1: segment-sum + relu/bias/dstn -> h (bf16) ------------------
__global__ void __launch_bounds__(256, 8)
gather_h_kernel(const int* __restrict__ offsets, const unsigned* __restrict__ edata,
                const unsigned short* __restrict__ xp, const float* __restrict__ dstn,
                const float* __restrict__ b1, unsigned short* __restrict__ hout, int N) {
    int lane = threadIdx.x & 63;
    int n = blockIdx.x * 4 + (threadIdx.x >> 6);
    if (n >= N) return;
    float acc = edge_gather(offsets, edata, xp, n, lane);
    float v = fmaxf(acc * dstn[n] + b1[lane], 0.0f);
    hout[(size_t)n * 64 + lane] = f2bf(v);
}

// ---- proj2: persistent; W2 in LDS; 16 nodes/wave in regs; readlane broadcast --
__global__ void proj2b_kernel(const unsigned short* __restrict__ h,
                              const float* __restrict__ X,
                              const float* __restrict__ W2, const float* __restrict__ srcn,
                              unsigned short* __restrict__ xp2, int N) {
    __shared__ float w[96 * 64];       // 24 KB, staged once
    int tid = threadIdx.x;
    {
        const float4* Wv = (const float4*)W2;
        float4* wv = (float4*)w;
        for (int i = tid; i < 1536; i += 256) wv[i] = Wv[i];
    }
    __syncthreads();
    int lane = tid & 63;
    int wid = tid >> 6;
    int half = lane >> 5;
    int col = lane & 31;
    int nt = (N + 15) >> 4;
    for (int t = blockIdx.x * 4 + wid; t < nt; t += gridDim.x * 4) {
        int n0 = t << 4;
        float xa[8], xb[8], xc[8];     // h cols [0,32), [32,64), X cols [0,32)
        if (n0 + 16 <= N) {
#pragma unroll
            for (int m = 0; m < 8; ++m) {
                int n = n0 + 2 * m + half;
                xa[m] = bf2f(h[(size_t)n * 64 + col]);
                xb[m] = bf2f(h[(size_t)n * 64 + 32 + col]);
                xc[m] = X[(size_t)n * 32 + col];
            }
        } else {
#pragma unroll
            for (int m = 0; m < 8; ++m) {
                int n = n0 + 2 * m + half;
                bool ok = (n < N);
                xa[m] = ok ? bf2f(h[(size_t)n * 64 + col]) : 0.f;
                xb[m] = ok ? bf2f(h[(size_t)n * 64 + 32 + col]) : 0.f;
                xc[m] = ok ? X[(size_t)n * 32 + col] : 0.f;
            }
        }
        float acc[16];
#pragma unroll
        for (int i = 0; i < 16; ++i) acc[i] = 0.f;
#pragma unroll 4
        for (int k = 0; k < 32; ++k) {
            float w0 = w[k * 64 + lane];
            float w1 = w[(32 + k) * 64 + lane];
            float w2v = w[(64 + k) * 64 + lane];
#pragma unroll
            for (int m = 0; m < 8; ++m) {
                float a0 = acc[2 * m], a1 = acc[2 * m + 1];
                a0 = fmaf(rlane(xa[m], k), w0, a0);
                a1 = fmaf(rlane(xa[m], 32 + k), w0, a1);
                a0 = fmaf(rlane(xb[m], k), w1, a0);
                a1 = fmaf(rlane(xb[m], 32 + k), w1, a1);
                a0 = fmaf(rlane(xc[m], k), w2v, a0);
                a1 = fmaf(rlane(xc[m], 32 + k), w2v, a1);
                acc[2 * m] = a0;
                acc[2 * m + 1] = a1;
            }
        }
#pragma unroll
        for (int i = 0; i < 16; ++i) {
            int n = n0 + i;
            if (n < N) xp2[(size_t)n * 64 + lane] = f2bf(acc[i] * srcn[n]);
        }
    }
}

// ---- final gather: layer-2 segment-sum + relu/bias/dstn + l2norm -> out -------
__global__ void __launch_bounds__(256, 8)
gather_final_kernel(const int* __restrict__ offsets, const unsigned* __restrict__ edata,
                    const unsigned short* __restrict__ xp2, const float* __restrict__ dstn,
                    const float* __restrict__ b2, float* __restrict__ out, int N) {
    int lane = threadIdx.x & 63;
    int n = blockIdx.x * 4 + (threadIdx.x >> 6);
    if (n >= N) return;
    float acc = edge_gather(offsets, edata, xp2, n, lane);
    float v = fmaxf(acc * dstn[n] + b2[lane], 0.0f);
    float s = v * v;
#pragma unroll
    for (int off = 32; off >= 1; off >>= 1) s += __shfl_xor(s, off, 64);
    v = v / fmaxf(sqrtf(s), 1e-12f);
    out[(size_t)n * 64 + lane] = v;
}

// ---------------- fallback path (atomic scatter) ---------------------------------
__global__ void deg_kernel_i(const int* __restrict__ src, const int* __restrict__ dst,
                             int* __restrict__ degs, int* __restrict__ degd, int E) {
    int i = blockIdx.x * blockDim.x + threadIdx.x;
    if (i < E) {
        atomicAdd(&degs[src[i]], 1);
        atomicAdd(&degd[dst[i]], 1);
    }
}

__global__ void norm_kernel_i(const int* __restrict__ degs, const int* __restrict__ degd,
                              float* __restrict__ srcn, float* __restrict__ dstn, int N) {
    int i = blockIdx.x * blockDim.x + threadIdx.x;
    if (i < N) {
        srcn[i] = rsqrtf(fmaxf((float)degs[i], 1.0f));
        dstn[i] = rsqrtf(fmaxf((float)degd[i], 1.0f));
    }
}

// f32-h projection for fallback layer 2 (h stored f32 in d_out)
__global__ void proj2f_kernel(const float* __restrict__ h, const float* __restrict__ X,
                              const float* __restrict__ W2, const float* __restrict__ srcn,
                              unsigned short* __restrict__ xp2, int N) {
    __shared__ float w[96 * 64];
    int tid = threadIdx.x;
    {
        const float4* Wv = (const float4*)W2;
        float4* wv = (float4*)w;
        for (int i = tid; i < 1536; i += 256) wv[i] = Wv[i];
    }
    __syncthreads();
    int lane = tid & 63;
    int wid = tid >> 6;
    int half = lane >> 5;
    int col = lane & 31;
    int nt = (N + 15) >> 4;
    for (int t = blockIdx.x * 4 + wid; t < nt; t += gridDim.x * 4) {
        int n0 = t << 4;
        float xa[8], xb[8], xc[8];
#pragma unroll
        for (int m = 0; m < 8; ++m) {
            int n = n0 + 2 * m + half;
            bool ok = (n < N);
            xa[m] = ok ? h[(size_t)n * 64 + col] : 0.f;
            xb[m] = ok ? h[(size_t)n * 64 + 32 + col] : 0.f;
            xc[m] = ok ? X[(size_t)n * 32 + col] : 0.f;
        }
        float acc[16];
#pragma unroll
        for (int i = 0; i < 16; ++i) acc[i] = 0.f;
#pragma unroll 4
        for (int k = 0; k < 32; ++k) {
            float w0 = w[k * 64 + lane];
            float w1 = w[(32 + k) * 64 + lane];
            float w2v = w[(64 + k) * 64 + lane];
#pragma unroll
            for (int m = 0; m < 8; ++m) {
                float a0 = acc[2 * m], a1 = acc[2 * m + 1];
                a0 = fmaf(rlane(xa[m], k), w0, a0);
                a1 = fmaf(rlane(xa[m], 32 + k), w0, a1);
                a0 = fmaf(rlane(xb[m], k), w1, a0);
                a1 = fmaf(rlane(xb[m], 32 + k), w1, a1);
                a0 = fmaf(rlane(xc[m], k), w2v, a0);
                a1 = fmaf(rlane(xc[m], 32 + k), w2v, a1);
                acc[2 * m] = a0;
                acc[2 * m + 1] = a1;
            }
        }
#pragma unroll
        for (int i = 0; i < 16; ++i) {
            int n = n0 + i;
            if (n < N) xp2[(size_t)n * 64 + lane] = f2bf(acc[i] * srcn[n]);
        }
    }
}

__global__ void scatter_kernel(const int* __restrict__ src, const int* __restrict__ dst,
                               const float* __restrict__ ew,
                               const unsigned short* __restrict__ xp,
                               float* __restrict__ acc, int E) {
    int total = E * 64;
    int stride = gridDim.x * blockDim.x;
    for (int i = blockIdx.x * blockDim.x + threadIdx.x; i < total; i += stride) {
        int e = i >> 6;
        int f = i & 63;
        int s = src[e];
        int d = dst[e];
        float v = bf2f(xp[(size_t)s * 64 + f]) * ew[e];
        atomicAdd(&acc[(size_t)d * 64 + f], v);
    }
}

__global__ void relu_bias_kernel(float* __restrict__ h, const float* __restrict__ dstn,
                                 const float* __restrict__ b, int N) {
    int i = blockIdx.x * blockDim.x + threadIdx.x;
    if (i < N * 64) {
        int n = i >> 6;
        int j = i & 63;
        h[i] = fmaxf(h[i] * dstn[n] + b[j], 0.0f);
    }
}

__global__ void finalize_kernel(float* __restrict__ out, const float* __restrict__ dstn,
                                const float* __restrict__ b, int N) {
    int i = blockIdx.x * blockDim.x + threadIdx.x;
    int n = i >> 6;
    int f = i & 63;
    if (n >= N) return;
    float v = fmaxf(out[(size_t)n * 64 + f] * dstn[n] + b[f], 0.0f);
    float s = v * v;
#pragma unroll
    for (int off = 32; off >= 1; off >>= 1) s += __shfl_xor(s, off, 64);
    out[(size_t)n * 64 + f] = v / fmaxf(sqrtf(s), 1e-12f);
}

// ---------------------------------------------------------------------------

extern "C" void kernel_launch(void* const* d_in, const int* in_sizes, int n_in,
                              void* d_out, int out_size, void* d_ws, size_t ws_size,
                              hipStream_t stream) {
    const float* X   = (const float*)d_in[0];   // [N,32]
    const float* ew  = (const float*)d_in[1];   // [E,1]
    const int*   src = (const int*)d_in[2];     // [E]
    const int*   dst = (const int*)d_in[3];     // [E]
    const float* W1  = (const float*)d_in[4];   // [32,64]
    const float* b1  = (const float*)d_in[5];   // [64]
    const float* W2  = (const float*)d_in[6];   // [96,64]
    const float* b2  = (const float*)d_in[7];   // [64]

    const int N = in_sizes[0] / 32;
    const int E = in_sizes[2];
    const int NW4 = (N + 3) / 4;                  // packed u8 quads (src hist)
    const int NBUK = (N + BUK - 1) / BUK;         // 128-node buckets
    const int M = NBUK * FSH;                     // count-matrix size
    const int L = (E + FSH - 1) / FSH;            // edges per pass-1 slice
    const int sliceS = (E + SS - 1) / SS;
    const int NBscan = (M + SCAN_CHUNK - 1) / SCAN_CHUNK;

    float* out = (float*)d_out;
    char* wsb = (char*)d_ws;

    // region I aliasing, in stream order:
    //   partial_s[SS*NW4 u32] -> inter[E uint2] -> { xp[N*64 bf16] | h[N*64 bf16] }
    size_t o = 0;
    auto alloc = [&](size_t bytes) { size_t p = o; o += (bytes + 255) & ~(size_t)255; return p; };
    size_t szPS = (size_t)SS * NW4 * 4;
    size_t szIN = (size_t)E * 8;
    size_t szXP = ((size_t)N * 64 * 2 + 255) & ~(size_t)255;
    size_t szH  = (size_t)N * 64 * 2;
    size_t szI = szPS > szIN ? szPS : szIN;
    if (szXP + szH > szI) szI = szXP + szH;
    size_t offI    = alloc(szI);
    size_t offEd   = alloc((size_t)E * 4);
    size_t offXP2  = alloc((size_t)N * 64 * 2);
    size_t offCS   = alloc(((size_t)M + 1) * 4);
    size_t offSrcn = alloc((size_t)N * 4);
    size_t offDstn = alloc((size_t)N * 4);
    size_t offOff  = alloc(((size_t)N + 1) * 4);
    size_t offBsum = alloc((size_t)NBscan * 4);
    size_t need = o;

    // u8 src-hist requires per-node degree < 256; u16 src pack requires N<=65536.
    bool ok = (ws_size >= need) && (N <= 65536) && (NBUK <= NBUK_MAX) &&
              ((size_t)NW4 * 4 <= MAX_LDS_BYTES);

    if (ok) {
        unsigned*       partial_s = (unsigned*)(wsb + offI);
        uint2*          inter     = (uint2*)(wsb + offI);
        unsigned short* xp        = (unsigned short*)(wsb + offI);
        unsigned short* hbuf      = (unsigned short*)(wsb + offI + szXP);
        unsigned*       edata     = (unsigned*)(wsb + offEd);
        unsigned short* xp2       = (unsigned short*)(wsb + offXP2);
        int*            cscan     = (int*)(wsb + offCS);
        float*          srcn      = (float*)(wsb + offSrcn);
        float*          dstn      = (float*)(wsb + offDstn);
        int*            offsets   = (int*)(wsb + offOff);
        int*            bsum      = (int*)(wsb + offBsum);

        // srcn from u8 LDS histogram
        hist_src_kernel<<<SS, HIST_BS, (size_t)NW4 * 4, stream>>>(src, partial_s, E, NW4, sliceS);
        reduce_src_kernel<<<(NW4 + 255) / 256, 256, 0, stream>>>(partial_s, srcn, N, NW4);

        // two-pass bucket radix: count -> scan (in-place) -> place -> finalize
        count_kernel<<<FSH, HIST_BS, 0, stream>>>(dst, cscan, E, L, NBUK);
        scan_partial<<<NBscan, SCAN_BS, 0, stream>>>(cscan, bsum, M);
        scan_bsums<<<1, 64, 0, stream>>>(bsum, NBscan);
        scan_final<<<NBscan, SCAN_BS, 0, stream>>>(cscan, bsum, cscan, M);
        place_seg_kernel<<<FSH, HIST_BS, 0, stream>>>(src, dst, ew, cscan, inter, E, L, NBUK);
        fill_final_kernel<<<NBUK, 256, 0, stream>>>(inter, cscan, edata, offsets, dstn, N, NBUK);

        // layer 1: project -> gather (+relu/bias/dstn) -> h (bf16)
        proj1_kernel<<<PROJ_GRID, 256, 0, stream>>>(X, W1, srcn, xp, N);
        gather_h_kernel<<<(N + 3) / 4, 256, 0, stream>>>(offsets, edata, xp, dstn, b1, hbuf, N);
        // layer 2: project concat(h,X) -> gather (+relu/bias/dstn+l2norm) -> out
        proj2b_kernel<<<PROJ_GRID, 256, 0, stream>>>(hbuf, X, W2, srcn, xp2, N);
        gather_final_kernel<<<(N + 3) / 4, 256, 0, stream>>>(offsets, edata, xp2, dstn,
                                                             b2, out, N);
    } else {
        // fallback: atomic-scatter pipeline
        float* ws   = (float*)d_ws;
        int*   degs = (int*)ws;
        int*   degd = (int*)(ws + N);
        float* srcn = ws + 2 * (size_t)N;
        float* dstn = ws + 3 * (size_t)N;
        unsigned short* xp = (unsigned short*)(ws + 4 * (size_t)N);

        hipMemsetAsync(degs, 0, 2 * (size_t)N * sizeof(float), stream);
        hipMemsetAsync(out, 0, (size_t)N * 64 * sizeof(float), stream);

        deg_kernel_i<<<(E + 255) / 256, 256, 0, stream>>>(src, dst, degs, degd, E);
        norm_kernel_i<<<(N + 255) / 256, 256, 0, stream>>>(degs, degd, srcn, dstn, N);

        proj1_kernel<<<PROJ_GRID, 256, 0, stream>>>(X, W1, srcn, xp, N);
        scatter_kernel<<<2048, 256, 0, stream>>>(src, dst, ew, xp, out, E);
        relu_bias_kernel<<<(N * 64 + 255) / 256, 256, 0, stream>>>(out, dstn, b1, N);

        proj2f_kernel<<<PROJ_GRID, 256, 0, stream>>>(out, X, W2, srcn, xp, N);
        hipMemsetAsync(out, 0, (size_t)N * 64 * sizeof(float), stream);
        scatter_kernel<<<2048, 256, 0, stream>>>(src, dst, ew, xp, out, E);
        finalize_kernel<<<(N * 64 + 255) / 256, 256, 0, stream>>>(out, dstn, b2, N);
    }
}

// Round 14
// 178.500 us; speedup vs baseline: 1.7539x; 1.1061x over previous
//
#include <hip/hip_runtime.h>
#include <math.h>

// ---------------------------------------------------------------------------
// GCN via two-pass bucket radix (dst-grouped edges, zero global atomics).
// h1 = relu(dstn * S(ew * srcn*(X@W1)) + b1)
// h2 = relu(dstn * S(ew * srcn*([h1,X]@W2)) + b2) ; out = l2norm(h2)
// Gathers: 1 wave = 2 nodes (half-wave each); 1 lane = 2 bf16 cols via packed
// uint loads; edge broadcast via one __shfl; bf16 unpack by masking only.
// Projections: persistent blocks; W in LDS; node rows in REGISTERS broadcast
// per-k via v_readlane (r12/r13: launch_bounds-capped VGPR -> scratch spill;
// no launch_bounds on reg-heavy kernels).
// xp,h bf16; edata packed u32 = src(16b) | bf16(ew). Assumes N<=65536, deg<256.
// ---------------------------------------------------------------------------

#define BUK 128              // nodes per bucket
#define BUK_SHIFT 7
#define FSH 256              // pass-1 edge slices (count/place blocks)
#define SS 128               // src-histogram slices
#define HIST_BS 512
#define NBUK_MAX 512
#define MAX_LDS_BYTES 131072
#define PROJ_GRID 512

#define SCAN_BS 256
#define SCAN_ITEMS 4
#define SCAN_CHUNK (SCAN_BS * SCAN_ITEMS)

__device__ __forceinline__ unsigned short f2bf(float f) {
    unsigned u = __float_as_uint(f);
    return (unsigned short)((u + 0x7fffu + ((u >> 16) & 1u)) >> 16);  // RNE
}
__device__ __forceinline__ float bf2f(unsigned short h) {
    return __uint_as_float((unsigned)h << 16);
}
__device__ __forceinline__ float bflo(unsigned u) {        // low bf16 of a uint
    return __uint_as_float(u << 16);
}
__device__ __forceinline__ float bfhi(unsigned u) {        // high bf16 of a uint
    return __uint_as_float(u & 0xffff0000u);
}
__device__ __forceinline__ float rlane(float v, int k) {
    return __uint_as_float(__builtin_amdgcn_readlane(__float_as_uint(v), k));
}

// ---- src out-degree histogram: per-slice packed u8 counts over N bins --------
__global__ void hist_src_kernel(const int* __restrict__ src, unsigned* __restrict__ partial_s,
                                int E, int NW4, int sliceS) {
    extern __shared__ unsigned h[];
    for (int i = threadIdx.x; i < NW4; i += blockDim.x) h[i] = 0u;
    __syncthreads();
    int s = blockIdx.x;
    int beg = s * sliceS, end = min(beg + sliceS, E);
    for (int e = beg + (int)threadIdx.x; e < end; e += blockDim.x) {
        int v = src[e];
        atomicAdd(&h[v >> 2], 1u << (8 * (v & 3)));
    }
    __syncthreads();
    unsigned* o = partial_s + (size_t)s * NW4;
    for (int i = threadIdx.x; i < NW4; i += blockDim.x) o[i] = h[i];
}

__global__ void reduce_src_kernel(const unsigned* __restrict__ partial_s,
                                  float* __restrict__ srcn, int N, int NW4) {
    int w = blockIdx.x * blockDim.x + threadIdx.x;
    if (w >= NW4) return;
    unsigned run = 0;
#pragma unroll 4
    for (int s = 0; s < SS; ++s) run += partial_s[(size_t)s * NW4 + w];
    int n0 = 4 * w;
#pragma unroll
    for (int k = 0; k < 4; ++k) {
        int n = n0 + k;
        if (n < N) srcn[n] = rsqrtf(fmaxf((float)((run >> (8 * k)) & 0xffu), 1.0f));
    }
}

// ---- per-slice bucket counts: cntmat[b*FSH + s] -------------------------------
__global__ void count_kernel(const int* __restrict__ dst, int* __restrict__ cntmat,
                             int E, int L, int NBUK) {
    __shared__ int c[NBUK_MAX];
    for (int i = threadIdx.x; i < NBUK; i += blockDim.x) c[i] = 0;
    __syncthreads();
    int s = blockIdx.x;
    int beg = s * L, end = min(beg + L, E);
    for (int e = beg + (int)threadIdx.x; e < end; e += blockDim.x)
        atomicAdd(&c[dst[e] >> BUK_SHIFT], 1);
    __syncthreads();
    for (int b = threadIdx.x; b < NBUK; b += blockDim.x)
        cntmat[(size_t)b * FSH + s] = c[b];
}

// ---- 3-kernel exclusive scan (generic, in-place capable) ----------------------
__global__ void scan_partial(const int* __restrict__ deg, int* __restrict__ bsum, int N) {
    __shared__ int sdata[SCAN_BS];
    int t = threadIdx.x;
    int base = blockIdx.x * SCAN_CHUNK + t * SCAN_ITEMS;
    int s = 0;
#pragma unroll
    for (int k = 0; k < SCAN_ITEMS; ++k) {
        int idx = base + k;
        s += (idx < N) ? deg[idx] : 0;
    }
    sdata[t] = s;
    __syncthreads();
    for (int off = SCAN_BS / 2; off > 0; off >>= 1) {
        if (t < off) sdata[t] += sdata[t + off];
        __syncthreads();
    }
    if (t == 0) bsum[blockIdx.x] = sdata[0];
}

__global__ void scan_bsums(int* __restrict__ bsum, int NB) {
    int carry = 0;
    for (int base = 0; base < NB; base += 64) {
        int l = base + (int)threadIdx.x;
        int v = (l < NB) ? bsum[l] : 0;
        int inc = v;
#pragma unroll
        for (int off = 1; off < 64; off <<= 1) {
            int tv = __shfl_up(inc, off, 64);
            if ((int)threadIdx.x >= off) inc += tv;
        }
        if (l < NB) bsum[l] = carry + inc - v;  // exclusive
        carry += __shfl(inc, 63, 64);
    }
}

__global__ void scan_final(const int* __restrict__ deg, const int* __restrict__ bsum,
                           int* __restrict__ offsets, int N) {
    __shared__ int sdata[SCAN_BS];
    int t = threadIdx.x;
    int base = blockIdx.x * SCAN_CHUNK + t * SCAN_ITEMS;
    int loc[SCAN_ITEMS];
    int s = 0;
#pragma unroll
    for (int k = 0; k < SCAN_ITEMS; ++k) {
        int idx = base + k;
        loc[k] = (idx < N) ? deg[idx] : 0;
        s += loc[k];
    }
    sdata[t] = s;
    __syncthreads();
    for (int off = 1; off < SCAN_BS; off <<= 1) {
        int v = (t >= off) ? sdata[t - off] : 0;
        __syncthreads();
        sdata[t] += v;
        __syncthreads();
    }
    int excl = sdata[t] - s + bsum[blockIdx.x];
#pragma unroll
    for (int k = 0; k < SCAN_ITEMS; ++k) {
        int idx = base + k;
        if (idx < N) {
            offsets[idx] = excl;
            if (idx == N - 1) offsets[N] = excl + loc[k];
        }
        excl += loc[k];
    }
}

// ---- pass 1: bin edges into per-(bucket,slice) contiguous segments ------------
__global__ void place_seg_kernel(const int* __restrict__ src, const int* __restrict__ dst,
                                 const float* __restrict__ ew, const int* __restrict__ cscan,
                                 uint2* __restrict__ inter, int E, int L, int NBUK) {
    __shared__ int cur[NBUK_MAX];
    int s = blockIdx.x;
    for (int b = threadIdx.x; b < NBUK; b += blockDim.x)
        cur[b] = cscan[(size_t)b * FSH + s];
    __syncthreads();
    int beg = s * L, end = min(beg + L, E);
    for (int e = beg + (int)threadIdx.x; e < end; e += blockDim.x) {
        int d = dst[e];
        int b = d >> BUK_SHIFT;
        int pos = atomicAdd(&cur[b], 1);
        inter[pos] = make_uint2((unsigned)src[e] | ((unsigned)f2bf(ew[e]) << 16),
                                (unsigned)(d & (BUK - 1)));
    }
}

// ---- pass 2: one block per bucket -> local degrees, offsets, dstn, final edata -
__global__ void fill_final_kernel(const uint2* __restrict__ inter,
                                  const int* __restrict__ cscan,
                                  unsigned* __restrict__ edata, int* __restrict__ offsets,
                                  float* __restrict__ dstn, int N, int NBUK) {
    __shared__ int cnt[BUK];
    __shared__ int loff[BUK];
    int b = blockIdx.x;
    int t = threadIdx.x;
    int beg = cscan[(size_t)b * FSH];
    int end = cscan[(size_t)(b + 1) * FSH];
    if (t < BUK) cnt[t] = 0;
    __syncthreads();
    for (int p = beg + t; p < end; p += blockDim.x)
        atomicAdd(&cnt[inter[p].y], 1);
    __syncthreads();
    if (t < 64) {
        int carry = 0;
#pragma unroll
        for (int base = 0; base < BUK; base += 64) {
            int v = cnt[base + t];
            int inc = v;
#pragma unroll
            for (int off = 1; off < 64; off <<= 1) {
                int tv = __shfl_up(inc, off, 64);
                if (t >= off) inc += tv;
            }
            loff[base + t] = carry + inc - v;
            carry += __shfl(inc, 63, 64);
        }
    }
    __syncthreads();
    int node0 = b << BUK_SHIFT;
    if (t < BUK) {
        int n = node0 + t;
        if (n < N) {
            offsets[n] = beg + loff[t];
            dstn[n] = rsqrtf(fmaxf((float)cnt[t], 1.0f));
        }
    }
    if (b == NBUK - 1 && t == 0) offsets[N] = end;
    __syncthreads();
    if (t < BUK) cnt[t] = 0;
    __syncthreads();
    for (int p = beg + t; p < end; p += blockDim.x) {
        uint2 r = inter[p];
        int dl = (int)r.y;
        int rk = atomicAdd(&cnt[dl], 1);
        edata[beg + loff[dl] + rk] = r.x;
    }
}

// ---- proj1: persistent; W1 in LDS; 16 nodes/wave in regs; readlane broadcast --
__global__ void proj1_kernel(const float* __restrict__ X, const float* __restrict__ W1,
                             const float* __restrict__ srcn,
                             unsigned short* __restrict__ xp, int N) {
    __shared__ float w[32 * 64];       // 8 KB, staged once
    int tid = threadIdx.x;
    {
        const float4* Wv = (const float4*)W1;
        float4* wv = (float4*)w;
        for (int i = tid; i < 512; i += 256) wv[i] = Wv[i];
    }
    __syncthreads();
    int lane = tid & 63;
    int wid = tid >> 6;
    int half = lane >> 5;              // 0: even node of pair, 1: odd node
    int col = lane & 31;
    int nt = (N + 15) >> 4;            // 16-node tiles
    for (int t = blockIdx.x * 4 + wid; t < nt; t += gridDim.x * 4) {
        int n0 = t << 4;
        float xv[8];
        if (n0 + 16 <= N) {
#pragma unroll
            for (int m = 0; m < 8; ++m)
                xv[m] = X[(size_t)(n0 + 2 * m + half) * 32 + col];
        } else {
#pragma unroll
            for (int m = 0; m < 8; ++m) {
                int n = n0 + 2 * m + half;
                xv[m] = (n < N) ? X[(size_t)n * 32 + col] : 0.f;
            }
        }
        float acc[16];
#pragma unroll
        for (int i = 0; i < 16; ++i) acc[i] = 0.f;
#pragma unroll 8
        for (int k = 0; k < 32; ++k) {
            float wk = w[k * 64 + lane];
#pragma unroll
            for (int m = 0; m < 8; ++m) {
                acc[2 * m]     = fmaf(rlane(xv[m], k), wk, acc[2 * m]);
                acc[2 * m + 1] = fmaf(rlane(xv[m], 32 + k), wk, acc[2 * m + 1]);
            }
        }
#pragma unroll
        for (int i = 0; i < 16; ++i) {
            int n = n0 + i;
            if (n < N) xp[(size_t)n * 64 + lane] = f2bf(acc[i] * srcn[n]);
        }
    }
}

// ---- gather: 1 wave = 2 nodes; lane = 2 cols (packed uint); template epilogue --
template <bool FINAL>
__global__ void gather2_kernel(const int* __restrict__ offsets,
                               const unsigned* __restrict__ edata,
                               const unsigned short* __restrict__ xp,
                               const float* __restrict__ dstn,
                               const float* __restrict__ bias,
                               void* __restrict__ outv, int N) {
    const unsigned* xpu = (const unsigned*)xp;
    int lane = threadIdx.x & 63;
    int c = lane & 31;
    int n = (blockIdx.x * 4 + (threadIdx.x >> 6)) * 2 + (lane >> 5);
    bool valid = (n < N);
    int beg = 0, end = 0;
    if (valid) { beg = offsets[n]; end = offsets[n + 1]; }
    int len = end - beg;
    int lenA = __builtin_amdgcn_readlane(len, 0);
    int lenB = __builtin_amdgcn_readlane(len, 32);
    int trips = ((lenA > lenB ? lenA : lenB) + 31) >> 5;
    float a0 = 0.f, a1 = 0.f, a2 = 0.f, a3 = 0.f;
    for (int t = 0; t < trips; ++t) {
        int p = beg + t * 32 + c;
        unsigned eb = (p < end) ? edata[p] : 0u;   // invalid -> ew bits = 0
#pragma unroll 8
        for (int k = 0; k < 32; k += 2) {
            unsigned ea = __shfl(eb, (lane & 32) + k, 64);
            unsigned ebv = __shfl(eb, (lane & 32) + k + 1, 64);
            unsigned pka = xpu[(size_t)(ea & 0xffffu) * 32 + c];
            unsigned pkb = xpu[(size_t)(ebv & 0xffffu) * 32 + c];
            float ewa = bfhi(ea);
            float ewb = bfhi(ebv);
            a0 = fmaf(bflo(pka), ewa, a0);
            a1 = fmaf(bfhi(pka), ewa, a1);
            a2 = fmaf(bflo(pkb), ewb, a2);
            a3 = fmaf(bfhi(pkb), ewb, a3);
        }
    }
    if (!valid) return;
    float s0 = a0 + a2;
    float s1 = a1 + a3;
    float dn = dstn[n];
    float2 bb = ((const float2*)bias)[c];
    float v0 = fmaxf(s0 * dn + bb.x, 0.f);
    float v1 = fmaxf(s1 * dn + bb.y, 0.f);
    if (FINAL) {
        float s = v0 * v0 + v1 * v1;
#pragma unroll
        for (int off = 16; off >= 1; off >>= 1) s += __shfl_xor(s, off, 64);
        float inv = 1.0f / fmaxf(sqrtf(s), 1e-12f);
        ((float2*)((float*)outv + (size_t)n * 64))[c] = make_float2(v0 * inv, v1 * inv);
    } else {
        ((unsigned*)outv)[(size_t)n * 32 + c] =
            (unsigned)f2bf(v0) | ((unsigned)f2bf(v1) << 16);
    }
}

// ---- proj2: persistent; W2 in LDS; 16 nodes/wave in regs; readlane broadcast --
__global__ void proj2b_kernel(const unsigned short* __restrict__ h,
                              const float* __restrict__ X,
                              const float* __restrict__ W2, const float* __restrict__ srcn,
                              unsigned short* __restrict__ xp2, int N) {
    __shared__ float w[96 * 64];       // 24 KB, staged once
    int tid = threadIdx.x;
    {
        const float4* Wv = (const float4*)W2;
        float4* wv = (float4*)w;
        for (int i = tid; i < 1536; i += 256) wv[i] = Wv[i];
    }
    __syncthreads();
    int lane = tid & 63;
    int wid = tid >> 6;
    int half = lane >> 5;
    int col = lane & 31;
    int nt = (N + 15) >> 4;
    for (int t = blockIdx.x * 4 + wid; t < nt; t += gridDim.x * 4) {
        int n0 = t << 4;
        float xa[8], xb[8], xc[8];
        if (n0 + 16 <= N) {
#pragma unroll
            for (int m = 0; m < 8; ++m) {
                int n = n0 + 2 * m + half;
                xa[m] = bf2f(h[(size_t)n * 64 + col]);
                xb[m] = bf2f(h[(size_t)n * 64 + 32 + col]);
                xc[m] = X[(size_t)n * 32 + col];
            }
        } else {
#pragma unroll
            for (int m = 0; m < 8; ++m) {
                int n = n0 + 2 * m + half;
                bool ok = (n < N);
                xa[m] = ok ? bf2f(h[(size_t)n * 64 + col]) : 0.f;
                xb[m] = ok ? bf2f(h[(size_t)n * 64 + 32 + col]) : 0.f;
                xc[m] = ok ? X[(size_t)n * 32 + col] : 0.f;
            }
        }
        float acc[16];
#pragma unroll
        for (int i = 0; i < 16; ++i) acc[i] = 0.f;
#pragma unroll 4
        for (int k = 0; k < 32; ++k) {
            float w0 = w[k * 64 + lane];
            float w1 = w[(32 + k) * 64 + lane];
            float w2v = w[(64 + k) * 64 + lane];
#pragma unroll
            for (int m = 0; m < 8; ++m) {
                float p0 = acc[2 * m], p1 = acc[2 * m + 1];
                p0 = fmaf(rlane(xa[m], k), w0, p0);
                p1 = fmaf(rlane(xa[m], 32 + k), w0, p1);
                p0 = fmaf(rlane(xb[m], k), w1, p0);
                p1 = fmaf(rlane(xb[m], 32 + k), w1, p1);
                p0 = fmaf(rlane(xc[m], k), w2v, p0);
                p1 = fmaf(rlane(xc[m], 32 + k), w2v, p1);
                acc[2 * m] = p0;
                acc[2 * m + 1] = p1;
            }
        }
#pragma unroll
        for (int i = 0; i < 16; ++i) {
            int n = n0 + i;
            if (n < N) xp2[(size_t)n * 64 + lane] = f2bf(acc[i] * srcn[n]);
        }
    }
}

// ---------------- fallback path (atomic scatter) ---------------------------------
__global__ void deg_kernel_i(const int* __restrict__ src, const int* __restrict__ dst,
                             int* __restrict__ degs, int* __restrict__ degd, int E) {
    int i = blockIdx.x * blockDim.x + threadIdx.x;
    if (i < E) {
        atomicAdd(&degs[src[i]], 1);
        atomicAdd(&degd[dst[i]], 1);
    }
}

__global__ void norm_kernel_i(const int* __restrict__ degs, const int* __restrict__ degd,
                              float* __restrict__ srcn, float* __restrict__ dstn, int N) {
    int i = blockIdx.x * blockDim.x + threadIdx.x;
    if (i < N) {
        srcn[i] = rsqrtf(fmaxf((float)degs[i], 1.0f));
        dstn[i] = rsqrtf(fmaxf((float)degd[i], 1.0f));
    }
}

// f32-h projection for fallback layer 2 (h stored f32 in d_out)
__global__ void proj2f_kernel(const float* __restrict__ h, const float* __restrict__ X,
                              const float* __restrict__ W2, const float* __restrict__ srcn,
                              unsigned short* __restrict__ xp2, int N) {
    __shared__ float w[96 * 64];
    int tid = threadIdx.x;
    {
        const float4* Wv = (const float4*)W2;
        float4* wv = (float4*)w;
        for (int i = tid; i < 1536; i += 256) wv[i] = Wv[i];
    }
    __syncthreads();
    int lane = tid & 63;
    int wid = tid >> 6;
    int half = lane >> 5;
    int col = lane & 31;
    int nt = (N + 15) >> 4;
    for (int t = blockIdx.x * 4 + wid; t < nt; t += gridDim.x * 4) {
        int n0 = t << 4;
        float xa[8], xb[8], xc[8];
#pragma unroll
        for (int m = 0; m < 8; ++m) {
            int n = n0 + 2 * m + half;
            bool ok = (n < N);
            xa[m] = ok ? h[(size_t)n * 64 + col] : 0.f;
            xb[m] = ok ? h[(size_t)n * 64 + 32 + col] : 0.f;
            xc[m] = ok ? X[(size_t)n * 32 + col] : 0.f;
        }
        float acc[16];
#pragma unroll
        for (int i = 0; i < 16; ++i) acc[i] = 0.f;
#pragma unroll 4
        for (int k = 0; k < 32; ++k) {
            float w0 = w[k * 64 + lane];
            float w1 = w[(32 + k) * 64 + lane];
            float w2v = w[(64 + k) * 64 + lane];
#pragma unroll
            for (int m = 0; m < 8; ++m) {
                float p0 = acc[2 * m], p1 = acc[2 * m + 1];
                p0 = fmaf(rlane(xa[m], k), w0, p0);
                p1 = fmaf(rlane(xa[m], 32 + k), w0, p1);
                p0 = fmaf(rlane(xb[m], k), w1, p0);
                p1 = fmaf(rlane(xb[m], 32 + k), w1, p1);
                p0 = fmaf(rlane(xc[m], k), w2v, p0);
                p1 = fmaf(rlane(xc[m], 32 + k), w2v, p1);
                acc[2 * m] = p0;
                acc[2 * m + 1] = p1;
            }
        }
#pragma unroll
        for (int i = 0; i < 16; ++i) {
            int n = n0 + i;
            if (n < N) xp2[(size_t)n * 64 + lane] = f2bf(acc[i] * srcn[n]);
        }
    }
}

__global__ void scatter_kernel(const int* __restrict__ src, const int* __restrict__ dst,
                               const float* __restrict__ ew,
                               const unsigned short* __restrict__ xp,
                               float* __restrict__ acc, int E) {
    int total = E * 64;
    int stride = gridDim.x * blockDim.x;
    for (int i = blockIdx.x * blockDim.x + threadIdx.x; i < total; i += stride) {
        int e = i >> 6;
        int f = i & 63;
        int s = src[e];
        int d = dst[e];
        float v = bf2f(xp[(size_t)s * 64 + f]) * ew[e];
        atomicAdd(&acc[(size_t)d * 64 + f], v);
    }
}

__global__ void relu_bias_kernel(float* __restrict__ h, const float* __restrict__ dstn,
                                 const float* __restrict__ b, int N) {
    int i = blockIdx.x * blockDim.x + threadIdx.x;
    if (i < N * 64) {
        int n = i >> 6;
        int j = i & 63;
        h[i] = fmaxf(h[i] * dstn[n] + b[j], 0.0f);
    }
}

__global__ void finalize_kernel(float* __restrict__ out, const float* __restrict__ dstn,
                                const float* __restrict__ b, int N) {
    int i = blockIdx.x * blockDim.x + threadIdx.x;
    int n = i >> 6;
    int f = i & 63;
    if (n >= N) return;
    float v = fmaxf(out[(size_t)n * 64 + f] * dstn[n] + b[f], 0.0f);
    float s = v * v;
#pragma unroll
    for (int off = 32; off >= 1; off >>= 1) s += __shfl_xor(s, off, 64);
    out[(size_t)n * 64 + f] = v / fmaxf(sqrtf(s), 1e-12f);
}

// ---------------------------------------------------------------------------

extern "C" void kernel_launch(void* const* d_in, const int* in_sizes, int n_in,
                              void* d_out, int out_size, void* d_ws, size_t ws_size,
                              hipStream_t stream) {
    const float* X   = (const float*)d_in[0];   // [N,32]
    const float* ew  = (const float*)d_in[1];   // [E,1]
    const int*   src = (const int*)d_in[2];     // [E]
    const int*   dst = (const int*)d_in[3];     // [E]
    const float* W1  = (const float*)d_in[4];   // [32,64]
    const float* b1  = (const float*)d_in[5];   // [64]
    const float* W2  = (const float*)d_in[6];   // [96,64]
    const float* b2  = (const float*)d_in[7];   // [64]

    const int N = in_sizes[0] / 32;
    const int E = in_sizes[2];
    const int NW4 = (N + 3) / 4;                  // packed u8 quads (src hist)
    const int NBUK = (N + BUK - 1) / BUK;         // 128-node buckets
    const int M = NBUK * FSH;                     // count-matrix size
    const int L = (E + FSH - 1) / FSH;            // edges per pass-1 slice
    const int sliceS = (E + SS - 1) / SS;
    const int NBscan = (M + SCAN_CHUNK - 1) / SCAN_CHUNK;
    const int gatherGrid = (((N + 1) / 2) + 3) / 4;   // 2 nodes/wave, 4 waves/block

    float* out = (float*)d_out;
    char* wsb = (char*)d_ws;

    // region I aliasing, in stream order:
    //   partial_s[SS*NW4 u32] -> inter[E uint2] -> { xp[N*64 bf16] | h[N*64 bf16] }
    size_t o = 0;
    auto alloc = [&](size_t bytes) { size_t p = o; o += (bytes + 255) & ~(size_t)255; return p; };
    size_t szPS = (size_t)SS * NW4 * 4;
    size_t szIN = (size_t)E * 8;
    size_t szXP = ((size_t)N * 64 * 2 + 255) & ~(size_t)255;
    size_t szH  = (size_t)N * 64 * 2;
    size_t szI = szPS > szIN ? szPS : szIN;
    if (szXP + szH > szI) szI = szXP + szH;
    size_t offI    = alloc(szI);
    size_t offEd   = alloc((size_t)E * 4);
    size_t offXP2  = alloc((size_t)N * 64 * 2);
    size_t offCS   = alloc(((size_t)M + 1) * 4);
    size_t offSrcn = alloc((size_t)N * 4);
    size_t offDstn = alloc((size_t)N * 4);
    size_t offOff  = alloc(((size_t)N + 1) * 4);
    size_t offBsum = alloc((size_t)NBscan * 4);
    size_t need = o;

    // u8 src-hist requires per-node degree < 256; u16 src pack requires N<=65536.
    bool ok = (ws_size >= need) && (N <= 65536) && (NBUK <= NBUK_MAX) &&
              ((size_t)NW4 * 4 <= MAX_LDS_BYTES);

    if (ok) {
        unsigned*       partial_s = (unsigned*)(wsb + offI);
        uint2*          inter     = (uint2*)(wsb + offI);
        unsigned short* xp        = (unsigned short*)(wsb + offI);
        unsigned short* hbuf      = (unsigned short*)(wsb + offI + szXP);
        unsigned*       edata     = (unsigned*)(wsb + offEd);
        unsigned short* xp2       = (unsigned short*)(wsb + offXP2);
        int*            cscan     = (int*)(wsb + offCS);
        float*          srcn      = (float*)(wsb + offSrcn);
        float*          dstn      = (float*)(wsb + offDstn);
        int*            offsets   = (int*)(wsb + offOff);
        int*            bsum      = (int*)(wsb + offBsum);

        // srcn from u8 LDS histogram
        hist_src_kernel<<<SS, HIST_BS, (size_t)NW4 * 4, stream>>>(src, partial_s, E, NW4, sliceS);
        reduce_src_kernel<<<(NW4 + 255) / 256, 256, 0, stream>>>(partial_s, srcn, N, NW4);

        // two-pass bucket radix: count -> scan (in-place) -> place -> finalize
        count_kernel<<<FSH, HIST_BS, 0, stream>>>(dst, cscan, E, L, NBUK);
        scan_partial<<<NBscan, SCAN_BS, 0, stream>>>(cscan, bsum, M);
        scan_bsums<<<1, 64, 0, stream>>>(bsum, NBscan);
        scan_final<<<NBscan, SCAN_BS, 0, stream>>>(cscan, bsum, cscan, M);
        place_seg_kernel<<<FSH, HIST_BS, 0, stream>>>(src, dst, ew, cscan, inter, E, L, NBUK);
        fill_final_kernel<<<NBUK, 256, 0, stream>>>(inter, cscan, edata, offsets, dstn, N, NBUK);

        // layer 1: project -> gather (+relu/bias/dstn) -> h (bf16)
        proj1_kernel<<<PROJ_GRID, 256, 0, stream>>>(X, W1, srcn, xp, N);
        gather2_kernel<false><<<gatherGrid, 256, 0, stream>>>(offsets, edata, xp, dstn,
                                                              b1, (void*)hbuf, N);
        // layer 2: project concat(h,X) -> gather (+relu/bias/dstn+l2norm) -> out
        proj2b_kernel<<<PROJ_GRID, 256, 0, stream>>>(hbuf, X, W2, srcn, xp2, N);
        gather2_kernel<true><<<gatherGrid, 256, 0, stream>>>(offsets, edata, xp2, dstn,
                                                             b2, (void*)out, N);
    } else {
        // fallback: atomic-scatter pipeline
        float* ws   = (float*)d_ws;
        int*   degs = (int*)ws;
        int*   degd = (int*)(ws + N);
        float* srcn = ws + 2 * (size_t)N;
        float* dstn = ws + 3 * (size_t)N;
        unsigned short* xp = (unsigned short*)(ws + 4 * (size_t)N);

        hipMemsetAsync(degs, 0, 2 * (size_t)N * sizeof(float), stream);
        hipMemsetAsync(out, 0, (size_t)N * 64 * sizeof(float), stream);

        deg_kernel_i<<<(E + 255) / 256, 256, 0, stream>>>(src, dst, degs, degd, E);
        norm_kernel_i<<<(N + 255) / 256, 256, 0, stream>>>(degs, degd, srcn, dstn, N);

        proj1_kernel<<<PROJ_GRID, 256, 0, stream>>>(X, W1, srcn, xp, N);
        scatter_kernel<<<2048, 256, 0, stream>>>(src, dst, ew, xp, out, E);
        relu_bias_kernel<<<(N * 64 + 255) / 256, 256, 0, stream>>>(out, dstn, b1, N);

        proj2f_kernel<<<PROJ_GRID, 256, 0, stream>>>(out, X, W2, srcn, xp, N);
        hipMemsetAsync(out, 0, (size_t)N * 64 * sizeof(float), stream);
        scatter_kernel<<<2048, 256, 0, stream>>>(src, dst, ew, xp, out, E);
        finalize_kernel<<<(N * 64 + 255) / 256, 256, 0, stream>>>(out, dstn, b2, N);
    }
}